// Round 1
// baseline (448.412 us; speedup 1.0000x reference)
//
#include <hip/hip_runtime.h>
#include <hip/hip_bf16.h>
#include <math.h>

// B=2, S=2048, H=2048, NH=16, HD=128
#define SEQ 2048
#define HID 2048
#define NHEAD 16
#define HDIM 128

typedef __bf16 bf16_t;
typedef __bf16 bf16x8 __attribute__((ext_vector_type(8)));
typedef __bf16 bf16x4_t __attribute__((ext_vector_type(4)));
typedef float f32x4 __attribute__((ext_vector_type(4)));

#define MFMA(a, b, c) __builtin_amdgcn_mfma_f32_16x16x32_bf16(a, b, c, 0, 0, 0)
#define GLOAD_LDS(g, l) \
  __builtin_amdgcn_global_load_lds((const __attribute__((address_space(1))) void*)(g), \
                                   (__attribute__((address_space(3))) void*)(l), 16, 0, 0)

// ---------------- cast kernels ----------------
__global__ void cast_hidden(const float* __restrict__ in, bf16_t* __restrict__ out) {
  int i = blockIdx.x * 256 + threadIdx.x;              // i indexes float4 groups; n4 = 2097152
  float4 v = ((const float4*)in)[i];
  bf16x4_t b;
  b[0] = (bf16_t)v.x; b[1] = (bf16_t)v.y; b[2] = (bf16_t)v.z; b[3] = (bf16_t)v.w;
  ((bf16x4_t*)out)[i] = b;
}

__global__ void cast_weights(const float* __restrict__ a, const float* __restrict__ b,
                             const float* __restrict__ c, const float* __restrict__ d,
                             bf16_t* __restrict__ out) {
  const float* srcs[4] = {a, b, c, d};
  const float* src = srcs[blockIdx.y];
  bf16_t* dst = out + (size_t)blockIdx.y * (HID * HID);
  int i = blockIdx.x * 256 + threadIdx.x;              // n4 = 1048576 per weight
  float4 v = ((const float4*)src)[i];
  bf16x4_t o;
  o[0] = (bf16_t)v.x; o[1] = (bf16_t)v.y; o[2] = (bf16_t)v.z; o[3] = (bf16_t)v.w;
  ((bf16x4_t*)dst)[i] = o;
}

// ---------------- GEMM: C = A * B^T  (A MxK, Bw NxK, both row-major bf16) ----------------
// m97 structure: 128x128 tile, BK=32, 4 waves (2x2), global_load_lds width 16.
__global__ __launch_bounds__(256, 2) void gemm_bt(
    const bf16_t* __restrict__ A, const bf16_t* __restrict__ Bw,
    bf16_t* __restrict__ Cb, float* __restrict__ Cf,
    int M, int N, int K) {
  __shared__ bf16_t As[128 * 32];
  __shared__ bf16_t Bs[128 * 32];
  const int tid = threadIdx.x;
  const int lane = tid & 63, wid = tid >> 6;
  const int wr = wid >> 1, wc = wid & 1;
  const int lr = lane & 15, lg = lane >> 4;
  const int brow = blockIdx.y, bcol = blockIdx.x;

  f32x4 acc[4][4] = {};

  for (int k0 = 0; k0 < K; k0 += 32) {
#pragma unroll
    for (int is = 0; is < 2; ++is) {
      int p = tid + is * 256;            // 512 positions of 16B each per tile
      int row = p >> 2, ch = p & 3;
      GLOAD_LDS(A + (size_t)(brow * 128 + row) * K + k0 + ch * 8, As + p * 8);
      GLOAD_LDS(Bw + (size_t)(bcol * 128 + row) * K + k0 + ch * 8, Bs + p * 8);
    }
    __syncthreads();
    bf16x8 af[4], bfr[4];
#pragma unroll
    for (int m = 0; m < 4; ++m)
      af[m] = *(const bf16x8*)(As + (wr * 64 + m * 16 + lr) * 32 + lg * 8);
#pragma unroll
    for (int n = 0; n < 4; ++n)
      bfr[n] = *(const bf16x8*)(Bs + (wc * 64 + n * 16 + lr) * 32 + lg * 8);
#pragma unroll
    for (int m = 0; m < 4; ++m)
#pragma unroll
      for (int n = 0; n < 4; ++n)
        acc[m][n] = MFMA(af[m], bfr[n], acc[m][n]);
    __syncthreads();
  }

#pragma unroll
  for (int m = 0; m < 4; ++m)
#pragma unroll
    for (int n = 0; n < 4; ++n)
#pragma unroll
      for (int r = 0; r < 4; ++r) {
        int row = brow * 128 + wr * 64 + m * 16 + lg * 4 + r;
        int col = bcol * 128 + wc * 64 + n * 16 + lr;
        float v = acc[m][n][r];
        if (Cf) Cf[(size_t)row * N + col] = v;
        else    Cb[(size_t)row * N + col] = (bf16_t)v;
      }
}

// ---------------- RoPE in-place on Qf, Kf (flat (B*S) x H, bf16) ----------------
__global__ void rope_qk(bf16_t* __restrict__ Q, bf16_t* __restrict__ K,
                        const float* __restrict__ cost, const float* __restrict__ sint) {
  int idx = blockIdx.x * 256 + threadIdx.x;            // total = 4096*16*64 = 4194304
  int d = idx & 63;
  int t = idx >> 6;
  int h = t & 15;
  int row = t >> 4;                                    // 0..4095 (= b*S+s)
  int s = row & (SEQ - 1);
  size_t base = (size_t)row * HID + h * HDIM;
  float c0 = cost[s * HDIM + d],      s0 = sint[s * HDIM + d];
  float c1 = cost[s * HDIM + d + 64], s1 = sint[s * HDIM + d + 64];
  float q0 = (float)Q[base + d], q1 = (float)Q[base + d + 64];
  Q[base + d]      = (bf16_t)(q0 * c0 - q1 * s0);
  Q[base + d + 64] = (bf16_t)(q1 * c1 + q0 * s1);
  float k0 = (float)K[base + d], k1 = (float)K[base + d + 64];
  K[base + d]      = (bf16_t)(k0 * c0 - k1 * s0);
  K[base + d + 64] = (bf16_t)(k1 * c1 + k0 * s1);
}

// ---------------- V transpose: Vf (B*S x H) -> Vt[b][h][d][s] ----------------
__global__ void transpose_v(const bf16_t* __restrict__ Vf, bf16_t* __restrict__ Vt) {
  __shared__ bf16_t t[32][33];
  int tx = threadIdx.x & 31, ty = threadIdx.x >> 5;    // 256 threads
  int r0 = blockIdx.y * 32, c0 = blockIdx.x * 32;
#pragma unroll
  for (int j = 0; j < 4; ++j)
    t[ty + j * 8][tx] = Vf[(size_t)(r0 + ty + j * 8) * HID + c0 + tx];
  __syncthreads();
#pragma unroll
  for (int j = 0; j < 4; ++j) {
    int c = c0 + ty + j * 8;                           // (h,d)
    int r = r0 + tx;                                   // (b,s)
    int h = c >> 7, d = c & 127, b = r >> 11, s = r & (SEQ - 1);
    Vt[(((size_t)(b * NHEAD + h)) * HDIM + d) * SEQ + s] = t[tx][ty + j * 8];
  }
}

// ---------------- flash attention fwd ----------------
// grid: (S/64, B*NH); 4 waves x 16 q-rows. K/Vt staged swizzled, P via per-wave LDS.
__global__ __launch_bounds__(256, 2) void flash_fwd(
    const bf16_t* __restrict__ Qf, const bf16_t* __restrict__ Kf,
    const bf16_t* __restrict__ Vt, const float* __restrict__ mask,
    bf16_t* __restrict__ AO) {
  __shared__ bf16_t Ks[64 * 128];
  __shared__ bf16_t Vs[128 * 64];
  __shared__ bf16_t Ps[4 * 16 * 64];
  const int tid = threadIdx.x, lane = tid & 63, wid = tid >> 6;
  const int lr = lane & 15, lg = lane >> 4;
  const int bh = blockIdx.y, b = bh >> 4, h = bh & 15;
  const int qw = blockIdx.x * 64 + wid * 16;

  // Q fragments (A-operand: row = lane&15, k-chunk = (lane>>4)*8)
  bf16x8 qf[4];
  const bf16_t* qrow = Qf + (size_t)(b * SEQ + qw + lr) * HID + h * HDIM;
#pragma unroll
  for (int kc = 0; kc < 4; ++kc)
    qf[kc] = *(const bf16x8*)(qrow + kc * 32 + lg * 8);

  float mrun[4], lrun[4];
#pragma unroll
  for (int r = 0; r < 4; ++r) { mrun[r] = -INFINITY; lrun[r] = 0.f; }
  f32x4 o[8] = {};

  const float scale = 0.08838834764831845f;  // 1/sqrt(128)
  char* KsB = (char*)Ks;
  char* VsB = (char*)Vs;
  char* PsB = (char*)Ps + wid * 2048;
  const float* mrow = mask + (size_t)b * SEQ * SEQ;

  for (int kt = 0; kt < SEQ / 64; ++kt) {
    const int kb0 = kt * 64;
    // stage K tile (64x128) and Vt tile (128x64), swizzled source -> linear LDS
#pragma unroll
    for (int is = 0; is < 4; ++is) {
      int p = tid + is * 256;
      {
        int row = p >> 4, ch = p & 15;
        int src = (ch * 16) ^ ((row & 7) << 4);
        GLOAD_LDS((const char*)(Kf + (size_t)(b * SEQ + kb0 + row) * HID + h * HDIM) + src,
                  KsB + p * 16);
      }
      {
        int row = p >> 3, ch = p & 7;
        int src = (ch * 16) ^ ((row & 7) << 4);
        GLOAD_LDS((const char*)(Vt + (size_t)(bh * HDIM + row) * SEQ + kb0) + src,
                  VsB + p * 16);
      }
    }
    __syncthreads();

    // QK^T: S_tile 16x64 per wave
    f32x4 sacc[4];
#pragma unroll
    for (int kb = 0; kb < 4; ++kb) {
      f32x4 z = {0.f, 0.f, 0.f, 0.f};
      sacc[kb] = z;
#pragma unroll
      for (int kc = 0; kc < 4; ++kc) {
        int row = kb * 16 + lr;
        bf16x8 kf = *(const bf16x8*)(KsB + row * 256 + ((kc * 64 + lg * 16) ^ ((row & 7) << 4)));
        sacc[kb] = MFMA(qf[kc], kf, sacc[kb]);
      }
    }

    // scale + mask (C layout: row=(lane>>4)*4+r, col=lane&15)
    float sv[4][4];
#pragma unroll
    for (int r = 0; r < 4; ++r) {
      int qg = qw + lg * 4 + r;
#pragma unroll
      for (int kb = 0; kb < 4; ++kb) {
        int kg = kb0 + kb * 16 + lr;
        sv[kb][r] = sacc[kb][r] * scale + mrow[(size_t)qg * SEQ + kg];
      }
    }

    // online softmax per q-row
#pragma unroll
    for (int r = 0; r < 4; ++r) {
      float mx = fmaxf(fmaxf(sv[0][r], sv[1][r]), fmaxf(sv[2][r], sv[3][r]));
      mx = fmaxf(mx, __shfl_xor(mx, 1, 64));
      mx = fmaxf(mx, __shfl_xor(mx, 2, 64));
      mx = fmaxf(mx, __shfl_xor(mx, 4, 64));
      mx = fmaxf(mx, __shfl_xor(mx, 8, 64));
      float mnew = fmaxf(mrun[r], mx);
      float corr = __expf(mrun[r] - mnew);
      mrun[r] = mnew;
      float rsum = 0.f;
#pragma unroll
      for (int kb = 0; kb < 4; ++kb) {
        float p = __expf(sv[kb][r] - mnew);
        sv[kb][r] = p;
        rsum += p;
      }
      rsum += __shfl_xor(rsum, 1, 64);
      rsum += __shfl_xor(rsum, 2, 64);
      rsum += __shfl_xor(rsum, 4, 64);
      rsum += __shfl_xor(rsum, 8, 64);
      lrun[r] = lrun[r] * corr + rsum;
#pragma unroll
      for (int nb = 0; nb < 8; ++nb) o[nb][r] *= corr;
    }

    // P -> LDS (bf16, swizzled), then PV
#pragma unroll
    for (int r = 0; r < 4; ++r) {
      int prow = lg * 4 + r;
#pragma unroll
      for (int kb = 0; kb < 4; ++kb) {
        int pcol = kb * 16 + lr;
        *(bf16_t*)(PsB + prow * 128 + ((pcol * 2) ^ ((prow & 7) << 4))) = (bf16_t)sv[kb][r];
      }
    }
#pragma unroll
    for (int kc2 = 0; kc2 < 2; ++kc2) {
      bf16x8 pf = *(const bf16x8*)(PsB + lr * 128 + ((kc2 * 64 + lg * 16) ^ ((lr & 7) << 4)));
#pragma unroll
      for (int nb = 0; nb < 8; ++nb) {
        int vrow = nb * 16 + lr;
        bf16x8 vf = *(const bf16x8*)(VsB + vrow * 128 + ((kc2 * 64 + lg * 16) ^ ((vrow & 7) << 4)));
        o[nb] = MFMA(pf, vf, o[nb]);
      }
    }
    __syncthreads();
  }

  // epilogue: O / l -> AO flat (B*S x H)
#pragma unroll
  for (int nb = 0; nb < 8; ++nb)
#pragma unroll
    for (int r = 0; r < 4; ++r) {
      int qg = qw + lg * 4 + r;
      int col = h * HDIM + nb * 16 + lr;
      AO[(size_t)(b * SEQ + qg) * HID + col] = (bf16_t)(o[nb][r] / lrun[r]);
    }
}

// ---------------- launch ----------------
extern "C" void kernel_launch(void* const* d_in, const int* in_sizes, int n_in,
                              void* d_out, int out_size, void* d_ws, size_t ws_size,
                              hipStream_t stream) {
  const float* hidden = (const float*)d_in[0];
  const float* cost   = (const float*)d_in[1];
  const float* sint   = (const float*)d_in[2];
  const float* mask   = (const float*)d_in[3];
  const float* Wq     = (const float*)d_in[4];
  const float* Wk     = (const float*)d_in[5];
  const float* Wv     = (const float*)d_in[6];
  const float* Wo     = (const float*)d_in[7];
  float* out = (float*)d_out;
  char* ws = (char*)d_ws;

  // workspace layout (bytes); AO aliases Af, Vt aliases dead Wqb/Wkb
  bf16_t* Af  = (bf16_t*)(ws + 0);          // 16.7 MB  (B*S x H)
  bf16_t* Wqb = (bf16_t*)(ws + 16777216);   // 8.4 MB x4 contiguous
  bf16_t* Wkb = (bf16_t*)(ws + 25165824);
  bf16_t* Wvb = (bf16_t*)(ws + 33554432);
  bf16_t* Wob = (bf16_t*)(ws + 41943040);
  bf16_t* Qf  = (bf16_t*)(ws + 50331648);
  bf16_t* Kf  = (bf16_t*)(ws + 67108864);
  bf16_t* Vf  = (bf16_t*)(ws + 83886080);
  bf16_t* Vt  = (bf16_t*)(ws + 16777216);   // alias Wqb+Wkb (dead after proj GEMMs)
  bf16_t* AO  = (bf16_t*)(ws + 0);          // alias Af (dead after proj GEMMs)

  cast_hidden<<<8192, 256, 0, stream>>>(hidden, Af);
  cast_weights<<<dim3(4096, 4), 256, 0, stream>>>(Wq, Wk, Wv, Wo, Wqb);

  gemm_bt<<<dim3(16, 32), 256, 0, stream>>>(Af, Wqb, Qf, nullptr, 4096, HID, HID);
  gemm_bt<<<dim3(16, 32), 256, 0, stream>>>(Af, Wkb, Kf, nullptr, 4096, HID, HID);
  gemm_bt<<<dim3(16, 32), 256, 0, stream>>>(Af, Wvb, Vf, nullptr, 4096, HID, HID);

  rope_qk<<<16384, 256, 0, stream>>>(Qf, Kf, cost, sint);
  transpose_v<<<dim3(64, 128), 256, 0, stream>>>(Vf, Vt);

  flash_fwd<<<dim3(SEQ / 64, 32), 256, 0, stream>>>(Qf, Kf, Vt, mask, AO);

  gemm_bt<<<dim3(16, 32), 256, 0, stream>>>(AO, Wob, nullptr, out, 4096, HID, HID);
}

// Round 2
// 365.288 us; speedup vs baseline: 1.2276x; 1.2276x over previous
//
#include <hip/hip_runtime.h>
#include <hip/hip_bf16.h>
#include <math.h>

// B=2, S=2048, H=2048, NH=16, HD=128
#define SEQ 2048
#define HID 2048
#define NHEAD 16
#define HDIM 128

typedef __bf16 bf16_t;
typedef __bf16 bf16x8 __attribute__((ext_vector_type(8)));
typedef __bf16 bf16x4_t __attribute__((ext_vector_type(4)));
typedef float f32x4 __attribute__((ext_vector_type(4)));

#define MFMA(a, b, c) __builtin_amdgcn_mfma_f32_16x16x32_bf16(a, b, c, 0, 0, 0)
#define GLOAD_LDS(g, l) \
  __builtin_amdgcn_global_load_lds((const __attribute__((address_space(1))) void*)(g), \
                                   (__attribute__((address_space(3))) void*)(l), 16, 0, 0)

// ---------------- cast kernels ----------------
__global__ void cast_hidden(const float* __restrict__ in, bf16_t* __restrict__ out) {
  int i = blockIdx.x * 256 + threadIdx.x;
  float4 v = ((const float4*)in)[i];
  bf16x4_t b;
  b[0] = (bf16_t)v.x; b[1] = (bf16_t)v.y; b[2] = (bf16_t)v.z; b[3] = (bf16_t)v.w;
  ((bf16x4_t*)out)[i] = b;
}

__global__ void cast_weights(const float* __restrict__ a, const float* __restrict__ b,
                             const float* __restrict__ c, const float* __restrict__ d,
                             bf16_t* __restrict__ out) {
  const float* srcs[4] = {a, b, c, d};
  const float* src = srcs[blockIdx.y];
  bf16_t* dst = out + (size_t)blockIdx.y * (HID * HID);
  int i = blockIdx.x * 256 + threadIdx.x;
  float4 v = ((const float4*)src)[i];
  bf16x4_t o;
  o[0] = (bf16_t)v.x; o[1] = (bf16_t)v.y; o[2] = (bf16_t)v.z; o[3] = (bf16_t)v.w;
  ((bf16x4_t*)dst)[i] = o;
}

// ---------------- GEMM: C = A * B^T, 2-phase double-buffered ----------------
// 128x128 tile, BK=32, 4 waves (2x2). 1D grid with XCD-bijective swizzle.
__global__ __launch_bounds__(256, 3) void gemm_bt(
    const bf16_t* __restrict__ A, const bf16_t* __restrict__ Bw,
    bf16_t* __restrict__ Cb, float* __restrict__ Cf,
    int M, int N, int K) {
  __shared__ bf16_t As[2][128 * 32];
  __shared__ bf16_t Bs[2][128 * 32];
  const int tid = threadIdx.x;
  const int lane = tid & 63, wid = tid >> 6;
  const int wr = wid >> 1, wc = wid & 1;
  const int lr = lane & 15, lg = lane >> 4;
  // XCD swizzle: grid is multiple of 8 (512 here)
  const int nwg = gridDim.x;
  const int lid = (blockIdx.x & 7) * (nwg >> 3) + (blockIdx.x >> 3);
  const int nbc = N >> 7;
  const int brow = lid / nbc, bcol = lid % nbc;

  f32x4 acc[4][4] = {};

  const int srow = tid >> 2, sch = tid & 3;           // 256 threads x (2 halves)
#define GSTAGE(k0, bb)                                                                   \
  {                                                                                      \
    _Pragma("unroll") for (int is = 0; is < 2; ++is) {                                   \
      int row = srow + is * 64;                                                          \
      GLOAD_LDS(A + (size_t)(brow * 128 + row) * K + (k0) + sch * 8,                     \
                &As[bb][(row * 4 + sch) * 8]);                                           \
      GLOAD_LDS(Bw + (size_t)(bcol * 128 + row) * K + (k0) + sch * 8,                    \
                &Bs[bb][(row * 4 + sch) * 8]);                                           \
    }                                                                                    \
  }

  GSTAGE(0, 0);
  __syncthreads();

  const int nt = K / 32;
  for (int t = 0; t < nt; ++t) {
    const int cb = t & 1;
    if (t + 1 < nt) GSTAGE((t + 1) * 32, cb ^ 1);
    bf16x8 af[4], bfr[4];
#pragma unroll
    for (int m = 0; m < 4; ++m)
      af[m] = *(const bf16x8*)(&As[cb][(wr * 64 + m * 16 + lr) * 32 + lg * 8]);
#pragma unroll
    for (int n = 0; n < 4; ++n)
      bfr[n] = *(const bf16x8*)(&Bs[cb][(wc * 64 + n * 16 + lr) * 32 + lg * 8]);
#pragma unroll
    for (int m = 0; m < 4; ++m)
#pragma unroll
      for (int n = 0; n < 4; ++n)
        acc[m][n] = MFMA(af[m], bfr[n], acc[m][n]);
    __syncthreads();
  }
#undef GSTAGE

#pragma unroll
  for (int m = 0; m < 4; ++m)
#pragma unroll
    for (int n = 0; n < 4; ++n)
#pragma unroll
      for (int r = 0; r < 4; ++r) {
        int row = brow * 128 + wr * 64 + m * 16 + lg * 4 + r;
        int col = bcol * 128 + wc * 64 + n * 16 + lr;
        float v = acc[m][n][r];
        if (Cf) Cf[(size_t)row * N + col] = v;
        else    Cb[(size_t)row * N + col] = (bf16_t)v;
      }
}

// ---------------- RoPE in-place on Qf, Kf (vectorized bf16x8) ----------------
__global__ void rope_qk(bf16_t* __restrict__ Q, bf16_t* __restrict__ K,
                        const float* __restrict__ cost, const float* __restrict__ sint) {
  int idx = blockIdx.x * 256 + threadIdx.x;            // total = 4096*16*8 = 524288
  int d8 = idx & 7;                                    // d = d8*8
  int t = idx >> 3;
  int h = t & 15;
  int row = t >> 4;
  int s = row & (SEQ - 1);
  size_t base = (size_t)row * HID + h * HDIM;
  const float4* cp = (const float4*)(cost + s * HDIM);
  const float4* sp = (const float4*)(sint + s * HDIM);
  float4 c0a = cp[d8 * 2], c0b = cp[d8 * 2 + 1];
  float4 c1a = cp[16 + d8 * 2], c1b = cp[16 + d8 * 2 + 1];
  float4 s0a = sp[d8 * 2], s0b = sp[d8 * 2 + 1];
  float4 s1a = sp[16 + d8 * 2], s1b = sp[16 + d8 * 2 + 1];
  float c0[8] = {c0a.x, c0a.y, c0a.z, c0a.w, c0b.x, c0b.y, c0b.z, c0b.w};
  float c1[8] = {c1a.x, c1a.y, c1a.z, c1a.w, c1b.x, c1b.y, c1b.z, c1b.w};
  float s0[8] = {s0a.x, s0a.y, s0a.z, s0a.w, s0b.x, s0b.y, s0b.z, s0b.w};
  float s1[8] = {s1a.x, s1a.y, s1a.z, s1a.w, s1b.x, s1b.y, s1b.z, s1b.w};

  bf16x8 qlo = *(bf16x8*)(Q + base + d8 * 8);
  bf16x8 qhi = *(bf16x8*)(Q + base + 64 + d8 * 8);
  bf16x8 klo = *(bf16x8*)(K + base + d8 * 8);
  bf16x8 khi = *(bf16x8*)(K + base + 64 + d8 * 8);
  bf16x8 qlo2, qhi2, klo2, khi2;
#pragma unroll
  for (int j = 0; j < 8; ++j) {
    float q0 = (float)qlo[j], q1 = (float)qhi[j];
    qlo2[j] = (bf16_t)(q0 * c0[j] - q1 * s0[j]);
    qhi2[j] = (bf16_t)(q1 * c1[j] + q0 * s1[j]);
    float k0 = (float)klo[j], k1 = (float)khi[j];
    klo2[j] = (bf16_t)(k0 * c0[j] - k1 * s0[j]);
    khi2[j] = (bf16_t)(k1 * c1[j] + k0 * s1[j]);
  }
  *(bf16x8*)(Q + base + d8 * 8) = qlo2;
  *(bf16x8*)(Q + base + 64 + d8 * 8) = qhi2;
  *(bf16x8*)(K + base + d8 * 8) = klo2;
  *(bf16x8*)(K + base + 64 + d8 * 8) = khi2;
}

// ---------------- V transpose: Vf (B*S x H) -> Vt[b][h][d][s] ----------------
__global__ void transpose_v(const bf16_t* __restrict__ Vf, bf16_t* __restrict__ Vt) {
  __shared__ bf16_t t[32][33];
  int tx = threadIdx.x & 31, ty = threadIdx.x >> 5;
  int r0 = blockIdx.y * 32, c0 = blockIdx.x * 32;
#pragma unroll
  for (int j = 0; j < 4; ++j)
    t[ty + j * 8][tx] = Vf[(size_t)(r0 + ty + j * 8) * HID + c0 + tx];
  __syncthreads();
#pragma unroll
  for (int j = 0; j < 4; ++j) {
    int c = c0 + ty + j * 8;
    int r = r0 + tx;
    int h = c >> 7, d = c & 127, b = r >> 11, s = r & (SEQ - 1);
    Vt[(((size_t)(b * NHEAD + h)) * HDIM + d) * SEQ + s] = t[tx][ty + j * 8];
  }
}

// ---------------- flash attention fwd: 2-phase pipelined, 32 q-rows/wave ----------------
// 1D grid 512 blocks (16 q-tiles x 32 bh), XCD-swizzled. 4 waves x 32 q-rows = 128 q/block.
__global__ __launch_bounds__(256, 2) void flash_fwd(
    const bf16_t* __restrict__ Qf, const bf16_t* __restrict__ Kf,
    const bf16_t* __restrict__ Vt, const float* __restrict__ mask,
    bf16_t* __restrict__ AO) {
  __shared__ char smem[73728];                          // K 2x16K | V 2x16K | P 4x2K
  char* KsB = smem;
  char* VsB = smem + 32768;
  const int tid = threadIdx.x, lane = tid & 63, wid = tid >> 6;
  const int lr = lane & 15, lg = lane >> 4;
  char* PsB = smem + 65536 + wid * 2048;

  const int lid = (blockIdx.x & 7) * 64 + (blockIdx.x >> 3);   // 512 blocks, bijective
  const int bh = lid >> 4, qt = lid & 15;
  const int b = bh >> 4, h = bh & 15;
  const int qbase = qt * 128 + wid * 32;

  // Q fragments: 2 q-groups x 4 k-chunks
  bf16x8 qf[2][4];
#pragma unroll
  for (int qs = 0; qs < 2; ++qs) {
    const bf16_t* qrow = Qf + (size_t)(b * SEQ + qbase + qs * 16 + lr) * HID + h * HDIM;
#pragma unroll
    for (int kc = 0; kc < 4; ++kc)
      qf[qs][kc] = *(const bf16x8*)(qrow + kc * 32 + lg * 8);
  }

  float mrun[2][4], lpart[2][4];
#pragma unroll
  for (int qs = 0; qs < 2; ++qs)
#pragma unroll
    for (int r = 0; r < 4; ++r) { mrun[qs][r] = -INFINITY; lpart[qs][r] = 0.f; }
  f32x4 o[2][8] = {};

  const float scale = 0.08838834764831845f;  // 1/sqrt(128)
  const float* mrow = mask + (size_t)b * SEQ * SEQ;

#define STAGE_KV(kt, bb)                                                                 \
  {                                                                                      \
    const int kb0_ = (kt) * 64;                                                          \
    _Pragma("unroll") for (int is = 0; is < 4; ++is) {                                   \
      int p = tid + is * 256;                                                            \
      int krow = p >> 4, kch = p & 15;                                                   \
      int ksrc = (kch * 16) ^ ((krow & 7) << 4);                                         \
      GLOAD_LDS((const char*)(Kf + (size_t)(b * SEQ + kb0_ + krow) * HID + h * HDIM) +    \
                    ksrc,                                                                \
                KsB + (bb) * 16384 + p * 16);                                            \
      int vrow = p >> 3, vch = p & 7;                                                    \
      int vsrc = (vch * 16) ^ ((vrow & 7) << 4);                                         \
      GLOAD_LDS((const char*)(Vt + (size_t)(bh * HDIM + vrow) * SEQ + kb0_) + vsrc,      \
                VsB + (bb) * 16384 + p * 16);                                            \
    }                                                                                    \
  }

  STAGE_KV(0, 0);
  __syncthreads();

  for (int kt = 0; kt < SEQ / 64; ++kt) {
    const int cur = kt & 1;
    const int kb0 = kt * 64;
    if (kt + 1 < SEQ / 64) STAGE_KV(kt + 1, cur ^ 1);

    // mask for this tile (overlaps QK^T)
    float mk[2][4][4];
#pragma unroll
    for (int qs = 0; qs < 2; ++qs)
#pragma unroll
      for (int r = 0; r < 4; ++r) {
        int qg = qbase + qs * 16 + lg * 4 + r;
#pragma unroll
        for (int kb = 0; kb < 4; ++kb)
          mk[qs][kb][r] = mrow[(size_t)qg * SEQ + kb0 + kb * 16 + lr];
      }

    // QK^T: both q-groups share K fragments
    f32x4 sacc[2][4] = {};
#pragma unroll
    for (int kb = 0; kb < 4; ++kb) {
      int row = kb * 16 + lr;
#pragma unroll
      for (int kc = 0; kc < 4; ++kc) {
        bf16x8 kf = *(const bf16x8*)(KsB + cur * 16384 + row * 256 +
                                     ((kc * 64 + lg * 16) ^ ((row & 7) << 4)));
        sacc[0][kb] = MFMA(qf[0][kc], kf, sacc[0][kb]);
        sacc[1][kb] = MFMA(qf[1][kc], kf, sacc[1][kb]);
      }
    }

#pragma unroll
    for (int qs = 0; qs < 2; ++qs) {
      // scale + mask
#pragma unroll
      for (int kb = 0; kb < 4; ++kb)
#pragma unroll
        for (int r = 0; r < 4; ++r)
          sacc[qs][kb][r] = sacc[qs][kb][r] * scale + mk[qs][kb][r];

      // row max (reduce over 16 lanes holding the row's 64 cols)
      float mx[4];
#pragma unroll
      for (int r = 0; r < 4; ++r) {
        float m0 = fmaxf(fmaxf(sacc[qs][0][r], sacc[qs][1][r]),
                         fmaxf(sacc[qs][2][r], sacc[qs][3][r]));
        m0 = fmaxf(m0, __shfl_xor(m0, 1, 64));
        m0 = fmaxf(m0, __shfl_xor(m0, 2, 64));
        m0 = fmaxf(m0, __shfl_xor(m0, 4, 64));
        m0 = fmaxf(m0, __shfl_xor(m0, 8, 64));
        mx[r] = m0;
      }
      // defer-max (T13): skip rescale when growth bounded
      bool okl = (mx[0] <= mrun[qs][0] + 8.f) && (mx[1] <= mrun[qs][1] + 8.f) &&
                 (mx[2] <= mrun[qs][2] + 8.f) && (mx[3] <= mrun[qs][3] + 8.f);
      if (!__all(okl)) {
#pragma unroll
        for (int r = 0; r < 4; ++r) {
          float mnew = fmaxf(mrun[qs][r], mx[r]);
          float corr = __expf(mrun[qs][r] - mnew);
          mrun[qs][r] = mnew;
          lpart[qs][r] *= corr;
#pragma unroll
          for (int nb = 0; nb < 8; ++nb) o[qs][nb][r] *= corr;
        }
      }

      // P = exp(s - m), per-lane partial row sum, store P to LDS (bf16, swizzled)
#pragma unroll
      for (int r = 0; r < 4; ++r) {
        int prow = lg * 4 + r;
        float rs = 0.f;
#pragma unroll
        for (int kb = 0; kb < 4; ++kb) {
          float p = __expf(sacc[qs][kb][r] - mrun[qs][r]);
          rs += p;
          int pcol = kb * 16 + lr;
          *(bf16_t*)(PsB + prow * 128 + ((pcol * 2) ^ ((prow & 7) << 4))) = (bf16_t)p;
        }
        lpart[qs][r] += rs;
      }

      // PV
#pragma unroll
      for (int ks = 0; ks < 2; ++ks) {
        bf16x8 pf = *(const bf16x8*)(PsB + lr * 128 +
                                     ((ks * 64 + lg * 16) ^ ((lr & 7) << 4)));
#pragma unroll
        for (int nb = 0; nb < 8; ++nb) {
          int vrow = nb * 16 + lr;
          bf16x8 vf = *(const bf16x8*)(VsB + cur * 16384 + vrow * 128 +
                                       ((ks * 64 + lg * 16) ^ ((vrow & 7) << 4)));
          o[qs][nb] = MFMA(pf, vf, o[qs][nb]);
        }
      }
    }
    __syncthreads();
  }
#undef STAGE_KV

  // epilogue: reduce per-lane partial sums, write O/l
#pragma unroll
  for (int qs = 0; qs < 2; ++qs)
#pragma unroll
    for (int r = 0; r < 4; ++r) {
      float l = lpart[qs][r];
      l += __shfl_xor(l, 1, 64);
      l += __shfl_xor(l, 2, 64);
      l += __shfl_xor(l, 4, 64);
      l += __shfl_xor(l, 8, 64);
      lpart[qs][r] = l;
    }
#pragma unroll
  for (int qs = 0; qs < 2; ++qs)
#pragma unroll
    for (int nb = 0; nb < 8; ++nb)
#pragma unroll
      for (int r = 0; r < 4; ++r) {
        int qg = qbase + qs * 16 + lg * 4 + r;
        AO[(size_t)(b * SEQ + qg) * HID + h * HDIM + nb * 16 + lr] =
            (bf16_t)(o[qs][nb][r] / lpart[qs][r]);
      }
}

// ---------------- launch ----------------
extern "C" void kernel_launch(void* const* d_in, const int* in_sizes, int n_in,
                              void* d_out, int out_size, void* d_ws, size_t ws_size,
                              hipStream_t stream) {
  const float* hidden = (const float*)d_in[0];
  const float* cost   = (const float*)d_in[1];
  const float* sint   = (const float*)d_in[2];
  const float* mask   = (const float*)d_in[3];
  const float* Wq     = (const float*)d_in[4];
  const float* Wk     = (const float*)d_in[5];
  const float* Wv     = (const float*)d_in[6];
  const float* Wo     = (const float*)d_in[7];
  float* out = (float*)d_out;
  char* ws = (char*)d_ws;

  bf16_t* Af  = (bf16_t*)(ws + 0);          // 16.7 MB  (B*S x H)
  bf16_t* Wqb = (bf16_t*)(ws + 16777216);
  bf16_t* Wkb = (bf16_t*)(ws + 25165824);
  bf16_t* Wvb = (bf16_t*)(ws + 33554432);
  bf16_t* Wob = (bf16_t*)(ws + 41943040);
  bf16_t* Qf  = (bf16_t*)(ws + 50331648);
  bf16_t* Kf  = (bf16_t*)(ws + 67108864);
  bf16_t* Vf  = (bf16_t*)(ws + 83886080);
  bf16_t* Vt  = (bf16_t*)(ws + 16777216);   // alias Wqb+Wkb (dead after Q/K GEMMs)
  bf16_t* AO  = (bf16_t*)(ws + 0);          // alias Af (dead after proj GEMMs)

  cast_hidden<<<8192, 256, 0, stream>>>(hidden, Af);
  cast_weights<<<dim3(4096, 4), 256, 0, stream>>>(Wq, Wk, Wv, Wo, Wqb);

  gemm_bt<<<512, 256, 0, stream>>>(Af, Wqb, Qf, nullptr, 4096, HID, HID);
  gemm_bt<<<512, 256, 0, stream>>>(Af, Wkb, Kf, nullptr, 4096, HID, HID);
  gemm_bt<<<512, 256, 0, stream>>>(Af, Wvb, Vf, nullptr, 4096, HID, HID);

  rope_qk<<<2048, 256, 0, stream>>>(Qf, Kf, cost, sint);
  transpose_v<<<dim3(64, 128), 256, 0, stream>>>(Vf, Vt);

  flash_fwd<<<512, 256, 0, stream>>>(Qf, Kf, Vt, mask, AO);

  gemm_bt<<<512, 256, 0, stream>>>(AO, Wob, nullptr, out, 4096, HID, HID);
}

// Round 3
// 331.352 us; speedup vs baseline: 1.3533x; 1.1024x over previous
//
#include <hip/hip_runtime.h>
#include <hip/hip_bf16.h>
#include <math.h>

// B=2, S=2048, H=2048, NH=16, HD=128
#define SEQ 2048
#define HID 2048
#define NHEAD 16
#define HDIM 128
#define LDQ 6144   // fused QKV row stride

typedef __bf16 bf16_t;
typedef __bf16 bf16x2 __attribute__((ext_vector_type(2)));
typedef __bf16 bf16x4_t __attribute__((ext_vector_type(4)));
typedef __bf16 bf16x8 __attribute__((ext_vector_type(8)));
typedef float f32x4 __attribute__((ext_vector_type(4)));
typedef float f32x16 __attribute__((ext_vector_type(16)));
typedef unsigned u32x4 __attribute__((ext_vector_type(4)));

#define MFMA16(a, b, c) __builtin_amdgcn_mfma_f32_16x16x32_bf16(a, b, c, 0, 0, 0)
#define MFMA32(a, b, c) __builtin_amdgcn_mfma_f32_32x32x16_bf16(a, b, c, 0, 0, 0)
#define GLOAD_LDS(g, l) \
  __builtin_amdgcn_global_load_lds((const __attribute__((address_space(1))) void*)(g), \
                                   (__attribute__((address_space(3))) void*)(l), 16, 0, 0)

static __device__ inline unsigned pk2(float lo, float hi) {
  bf16x2 t; t[0] = (bf16_t)lo; t[1] = (bf16_t)hi;
  return __builtin_bit_cast(unsigned, t);
}

// ---------------- cast kernels ----------------
__global__ void cast_hidden(const float* __restrict__ in, bf16_t* __restrict__ out) {
  int i = blockIdx.x * 256 + threadIdx.x;
  float4 v = ((const float4*)in)[i];
  bf16x4_t b;
  b[0] = (bf16_t)v.x; b[1] = (bf16_t)v.y; b[2] = (bf16_t)v.z; b[3] = (bf16_t)v.w;
  ((bf16x4_t*)out)[i] = b;
}

__global__ void cast_weights(const float* __restrict__ a, const float* __restrict__ b,
                             const float* __restrict__ c, const float* __restrict__ d,
                             bf16_t* __restrict__ out) {
  const float* srcs[4] = {a, b, c, d};
  const float* src = srcs[blockIdx.y];
  bf16_t* dst = out + (size_t)blockIdx.y * (HID * HID);
  int i = blockIdx.x * 256 + threadIdx.x;
  float4 v = ((const float4*)src)[i];
  bf16x4_t o;
  o[0] = (bf16_t)v.x; o[1] = (bf16_t)v.y; o[2] = (bf16_t)v.z; o[3] = (bf16_t)v.w;
  ((bf16x4_t*)dst)[i] = o;
}

// ---------------- GEMM: C = A * B^T, 2-phase double-buffered ----------------
__global__ __launch_bounds__(256, 3) void gemm_bt(
    const bf16_t* __restrict__ A, const bf16_t* __restrict__ Bw,
    bf16_t* __restrict__ Cb, float* __restrict__ Cf,
    int M, int N, int K) {
  __shared__ bf16_t As[2][128 * 32];
  __shared__ bf16_t Bs[2][128 * 32];
  const int tid = threadIdx.x;
  const int lane = tid & 63, wid = tid >> 6;
  const int wr = wid >> 1, wc = wid & 1;
  const int lr = lane & 15, lg = lane >> 4;
  const int nwg = gridDim.x;
  const int lid = (blockIdx.x & 7) * (nwg >> 3) + (blockIdx.x >> 3);
  const int nbc = N >> 7;
  const int brow = lid / nbc, bcol = lid % nbc;

  f32x4 acc[4][4] = {};

  const int srow = tid >> 2, sch = tid & 3;
#define GSTAGE(k0, bb)                                                                   \
  {                                                                                      \
    _Pragma("unroll") for (int is = 0; is < 2; ++is) {                                   \
      int row = srow + is * 64;                                                          \
      GLOAD_LDS(A + (size_t)(brow * 128 + row) * K + (k0) + sch * 8,                     \
                &As[bb][(row * 4 + sch) * 8]);                                           \
      GLOAD_LDS(Bw + (size_t)(bcol * 128 + row) * K + (k0) + sch * 8,                    \
                &Bs[bb][(row * 4 + sch) * 8]);                                           \
    }                                                                                    \
  }

  GSTAGE(0, 0);
  __syncthreads();

  const int nt = K / 32;
  for (int t = 0; t < nt; ++t) {
    const int cb = t & 1;
    if (t + 1 < nt) GSTAGE((t + 1) * 32, cb ^ 1);
    bf16x8 af[4], bfr[4];
#pragma unroll
    for (int m = 0; m < 4; ++m)
      af[m] = *(const bf16x8*)(&As[cb][(wr * 64 + m * 16 + lr) * 32 + lg * 8]);
#pragma unroll
    for (int n = 0; n < 4; ++n)
      bfr[n] = *(const bf16x8*)(&Bs[cb][(wc * 64 + n * 16 + lr) * 32 + lg * 8]);
#pragma unroll
    for (int m = 0; m < 4; ++m)
#pragma unroll
      for (int n = 0; n < 4; ++n)
        acc[m][n] = MFMA16(af[m], bfr[n], acc[m][n]);
    __syncthreads();
  }
#undef GSTAGE

#pragma unroll
  for (int m = 0; m < 4; ++m)
#pragma unroll
    for (int n = 0; n < 4; ++n)
#pragma unroll
      for (int r = 0; r < 4; ++r) {
        int row = brow * 128 + wr * 64 + m * 16 + lg * 4 + r;
        int col = bcol * 128 + wc * 64 + n * 16 + lr;
        float v = acc[m][n][r];
        if (Cf) Cf[(size_t)row * N + col] = v;
        else    Cb[(size_t)row * N + col] = (bf16_t)v;
      }
}

// ---------------- RoPE in-place on fused QKV (Q gets pre-scaled by 1/sqrt(HD)) ----------
__global__ void rope_qk(bf16_t* __restrict__ QKV,
                        const float* __restrict__ cost, const float* __restrict__ sint) {
  const float SCALE = 0.08838834764831845f;  // 1/sqrt(128)
  int idx = blockIdx.x * 256 + threadIdx.x;            // total = 4096*16*8 = 524288
  int d8 = idx & 7;
  int t = idx >> 3;
  int h = t & 15;
  int row = t >> 4;
  int s = row & (SEQ - 1);
  size_t base = (size_t)row * LDQ + h * HDIM;
  const float4* cp = (const float4*)(cost + s * HDIM);
  const float4* sp = (const float4*)(sint + s * HDIM);
  float4 c0a = cp[d8 * 2], c0b = cp[d8 * 2 + 1];
  float4 c1a = cp[16 + d8 * 2], c1b = cp[16 + d8 * 2 + 1];
  float4 s0a = sp[d8 * 2], s0b = sp[d8 * 2 + 1];
  float4 s1a = sp[16 + d8 * 2], s1b = sp[16 + d8 * 2 + 1];
  float c0[8] = {c0a.x, c0a.y, c0a.z, c0a.w, c0b.x, c0b.y, c0b.z, c0b.w};
  float c1[8] = {c1a.x, c1a.y, c1a.z, c1a.w, c1b.x, c1b.y, c1b.z, c1b.w};
  float s0[8] = {s0a.x, s0a.y, s0a.z, s0a.w, s0b.x, s0b.y, s0b.z, s0b.w};
  float s1[8] = {s1a.x, s1a.y, s1a.z, s1a.w, s1b.x, s1b.y, s1b.z, s1b.w};

  bf16_t* Q = QKV;
  bf16_t* K = QKV + 2048;
  bf16x8 qlo = *(bf16x8*)(Q + base + d8 * 8);
  bf16x8 qhi = *(bf16x8*)(Q + base + 64 + d8 * 8);
  bf16x8 klo = *(bf16x8*)(K + base + d8 * 8);
  bf16x8 khi = *(bf16x8*)(K + base + 64 + d8 * 8);
  bf16x8 qlo2, qhi2, klo2, khi2;
#pragma unroll
  for (int j = 0; j < 8; ++j) {
    float q0 = (float)qlo[j], q1 = (float)qhi[j];
    qlo2[j] = (bf16_t)((q0 * c0[j] - q1 * s0[j]) * SCALE);
    qhi2[j] = (bf16_t)((q1 * c1[j] + q0 * s1[j]) * SCALE);
    float k0 = (float)klo[j], k1 = (float)khi[j];
    klo2[j] = (bf16_t)(k0 * c0[j] - k1 * s0[j]);
    khi2[j] = (bf16_t)(k1 * c1[j] + k0 * s1[j]);
  }
  *(bf16x8*)(Q + base + d8 * 8) = qlo2;
  *(bf16x8*)(Q + base + 64 + d8 * 8) = qhi2;
  *(bf16x8*)(K + base + d8 * 8) = klo2;
  *(bf16x8*)(K + base + 64 + d8 * 8) = khi2;
}

// ---------------- V transpose: Vf (B*S x H, ld=LDQ) -> Vt[b][h][d][s] ----------------
__global__ void transpose_v(const bf16_t* __restrict__ Vf, bf16_t* __restrict__ Vt) {
  __shared__ bf16_t t[32][33];
  int tx = threadIdx.x & 31, ty = threadIdx.x >> 5;
  int r0 = blockIdx.y * 32, c0 = blockIdx.x * 32;
#pragma unroll
  for (int j = 0; j < 4; ++j)
    t[ty + j * 8][tx] = Vf[(size_t)(r0 + ty + j * 8) * LDQ + c0 + tx];
  __syncthreads();
#pragma unroll
  for (int j = 0; j < 4; ++j) {
    int c = c0 + ty + j * 8;
    int r = r0 + tx;
    int h = c >> 7, d = c & 127, b = r >> 11, s = r & (SEQ - 1);
    Vt[(((size_t)(b * NHEAD + h)) * HDIM + d) * SEQ + s] = t[tx][ty + j * 8];
  }
}

// ---------------- flash attention fwd: swapped-QK 32x32, in-register softmax ----------
// 8 waves x 32 q-rows = 256 q/block. KVBLK=128 double-buffered (128 KB LDS).
// grid: 256 blocks, blockIdx = qt*32 + bh (same-bh blocks co-XCD).
__global__ __launch_bounds__(512, 2) void flash_fwd(
    const bf16_t* __restrict__ Qf, const bf16_t* __restrict__ Kf,
    const bf16_t* __restrict__ Vt, const float* __restrict__ mask,
    bf16_t* __restrict__ AO) {
  __shared__ char smem[131072];          // K 2x32K | V 2x32K
  char* KsB = smem;
  char* VsB = smem + 65536;
  const int tid = threadIdx.x, lane = tid & 63, wid = tid >> 6;
  const int q32 = lane & 31, hi = lane >> 5;

  const int x = blockIdx.x;
  const int bh = x & 31, qt = x >> 5;
  const int b = bh >> 4, h = bh & 15;
  const int qg = qt * 256 + wid * 32 + q32;

  // Q fragments (B-operand): lane holds Q[q=lane&31][d = ds*16 + hi*8 + j]
  bf16x8 qf[8];
  const bf16_t* qptr = Qf + (size_t)(b * SEQ + qg) * LDQ + h * HDIM + hi * 8;
#pragma unroll
  for (int ds = 0; ds < 8; ++ds) qf[ds] = *(const bf16x8*)(qptr + ds * 16);

  const float* mp = mask + (size_t)b * SEQ * SEQ + (size_t)qg * SEQ + hi * 4;

  float mrun = -INFINITY, lpart = 0.f;
  f32x16 o[4] = {};

#define STAGE_KV(kt_, bb)                                                                \
  {                                                                                      \
    const int kb0_ = (kt_) * 128;                                                        \
    _Pragma("unroll") for (int is = 0; is < 4; ++is) {                                   \
      int p = tid + is * 512;                                                            \
      int row = p >> 4, ch = p & 15;                                                     \
      int src = (ch * 16) ^ ((row & 7) << 4);                                            \
      GLOAD_LDS((const char*)(Kf + (size_t)(b * SEQ + kb0_ + row) * LDQ + h * HDIM) +    \
                    src,                                                                 \
                KsB + (bb) * 32768 + p * 16);                                            \
      GLOAD_LDS((const char*)(Vt + (size_t)(bh * HDIM + row) * SEQ + kb0_) + src,        \
                VsB + (bb) * 32768 + p * 16);                                            \
    }                                                                                    \
  }

  STAGE_KV(0, 0);
  __syncthreads();

  const int NT = SEQ / 128;
  for (int kt = 0; kt < NT; ++kt) {
    const int cur = kt & 1;
    const int kb0 = kt * 128;
    if (kt + 1 < NT) STAGE_KV(kt + 1, cur ^ 1);

#pragma unroll
    for (int kb = 0; kb < 4; ++kb) {
      // init accumulator with mask (C[key][q]: key = (reg&3)+8*(reg>>2)+4*hi)
      f32x16 sacc;
#pragma unroll
      for (int g = 0; g < 4; ++g) {
        float4 m4 = *(const float4*)(mp + kb0 + kb * 32 + 8 * g);
        sacc[4 * g + 0] = m4.x; sacc[4 * g + 1] = m4.y;
        sacc[4 * g + 2] = m4.z; sacc[4 * g + 3] = m4.w;
      }
      // QK^T over d=128: A = K frag from LDS (row=key, k=d)
#pragma unroll
      for (int ds = 0; ds < 8; ++ds) {
        int row = kb * 32 + q32;
        bf16x8 kfr = *(const bf16x8*)(KsB + cur * 32768 + row * 256 +
                                      ((ds * 32 + hi * 16) ^ ((row & 7) << 4)));
        sacc = MFMA32(kfr, qf[ds], sacc);
      }

      // row max over this 32-key group (lane pair shares q)
      float mx = sacc[0];
#pragma unroll
      for (int r = 1; r < 16; ++r) mx = fmaxf(mx, sacc[r]);
      mx = fmaxf(mx, __shfl_xor(mx, 32, 64));
      // defer-max (T13)
      if (!__all(mx <= mrun + 8.f)) {
        float mnew = fmaxf(mrun, mx);
        float corr = __expf(mrun - mnew);
        mrun = mnew;
        lpart *= corr;
#pragma unroll
        for (int d0 = 0; d0 < 4; ++d0)
#pragma unroll
          for (int r = 0; r < 16; ++r) o[d0][r] *= corr;
      }

      // P = exp(s - m); per-lane partial row sum
      float p[16];
      float rs = 0.f;
#pragma unroll
      for (int r = 0; r < 16; ++r) {
        p[r] = __expf(sacc[r] - mrun);
        rs += p[r];
      }
      lpart += rs;

      // re-layout P to PV B-fragments and run PV for this 32-key group
#pragma unroll
      for (int s = 0; s < 2; ++s) {
        unsigned A1 = pk2(p[8 * s + 0], p[8 * s + 1]);
        unsigned A2 = pk2(p[8 * s + 2], p[8 * s + 3]);
        unsigned B1 = pk2(p[8 * s + 4], p[8 * s + 5]);
        unsigned B2 = pk2(p[8 * s + 6], p[8 * s + 7]);
        unsigned A1s = __shfl_xor(A1, 32, 64);
        unsigned A2s = __shfl_xor(A2, 32, 64);
        unsigned B1s = __shfl_xor(B1, 32, 64);
        unsigned B2s = __shfl_xor(B2, 32, 64);
        unsigned w0 = hi ? B1s : A1;
        unsigned w1 = hi ? B2s : A2;
        unsigned w2 = hi ? B1 : A1s;
        unsigned w3 = hi ? B2 : A2s;
        u32x4 W = {w0, w1, w2, w3};
        bf16x8 pav = __builtin_bit_cast(bf16x8, W);
        const int gs = kb * 2 + s;   // 16-key slice index within the 128-key tile
#pragma unroll
        for (int d0 = 0; d0 < 4; ++d0) {
          int vrow = d0 * 32 + q32;
          bf16x8 vf = *(const bf16x8*)(VsB + cur * 32768 + vrow * 256 +
                                       ((gs * 32 + hi * 16) ^ ((vrow & 7) << 4)));
          o[d0] = MFMA32(vf, pav, o[d0]);
        }
      }
    }
    __syncthreads();
  }
#undef STAGE_KV

  // epilogue: full row sum, normalize, write AO (pack bf16 pairs)
  float l = lpart + __shfl_xor(lpart, 32, 64);
  float rl = 1.f / l;
  bf16_t* aorow = AO + (size_t)(b * SEQ + qg) * HID + h * HDIM;
#pragma unroll
  for (int d0 = 0; d0 < 4; ++d0)
#pragma unroll
    for (int g = 0; g < 4; ++g) {
      unsigned lo = pk2(o[d0][4 * g + 0] * rl, o[d0][4 * g + 1] * rl);
      unsigned hi2 = pk2(o[d0][4 * g + 2] * rl, o[d0][4 * g + 3] * rl);
      int d = d0 * 32 + 8 * g + 4 * hi;
      *(unsigned*)(aorow + d) = lo;
      *(unsigned*)(aorow + d + 2) = hi2;
    }
}

// ---------------- launch ----------------
extern "C" void kernel_launch(void* const* d_in, const int* in_sizes, int n_in,
                              void* d_out, int out_size, void* d_ws, size_t ws_size,
                              hipStream_t stream) {
  const float* hidden = (const float*)d_in[0];
  const float* cost   = (const float*)d_in[1];
  const float* sint   = (const float*)d_in[2];
  const float* mask   = (const float*)d_in[3];
  const float* Wq     = (const float*)d_in[4];
  const float* Wk     = (const float*)d_in[5];
  const float* Wv     = (const float*)d_in[6];
  const float* Wo     = (const float*)d_in[7];
  float* out = (float*)d_out;
  char* ws = (char*)d_ws;

  // layout (bytes):
  //   Af   @ 0          16.78 MB  (dead after QKV gemm)
  //   Vt   @ 0          16.78 MB  (alias Af; live transpose..flash)
  //   AO   @ 16777216   16.78 MB  (alias Wqb+Wkb; live flash..final gemm)
  //   Wqb..Wob @ 16777216 + i*8388608  (Wob @ 41943040 stays live)
  //   QKV  @ 50331648   50.33 MB  (4096 x 6144 bf16)
  bf16_t* Af  = (bf16_t*)(ws + 0);
  bf16_t* Wqb = (bf16_t*)(ws + 16777216);
  bf16_t* Wob = (bf16_t*)(ws + 41943040);
  bf16_t* QKV = (bf16_t*)(ws + 50331648);
  bf16_t* Vt  = (bf16_t*)(ws + 0);
  bf16_t* AO  = (bf16_t*)(ws + 16777216);

  cast_hidden<<<8192, 256, 0, stream>>>(hidden, Af);
  cast_weights<<<dim3(4096, 4), 256, 0, stream>>>(Wq, Wk, Wv, Wo, Wqb);

  // fused QKV projection: A(4096x2048) * [Wq;Wk;Wv]^T (6144x2048) -> QKV
  gemm_bt<<<1536, 256, 0, stream>>>(Af, Wqb, QKV, nullptr, 4096, LDQ, HID);

  rope_qk<<<2048, 256, 0, stream>>>(QKV, cost, sint);
  transpose_v<<<dim3(64, 128), 256, 0, stream>>>(QKV + 4096, Vt);

  flash_fwd<<<256, 512, 0, stream>>>(QKV, QKV + 2048, Vt, mask, AO);

  gemm_bt<<<512, 256, 0, stream>>>(AO, Wob, nullptr, out, 4096, HID, HID);
}

// Round 4
// 324.846 us; speedup vs baseline: 1.3804x; 1.0200x over previous
//
#include <hip/hip_runtime.h>
#include <hip/hip_bf16.h>
#include <math.h>

// B=2, S=2048, H=2048, NH=16, HD=128
#define SEQ 2048
#define HID 2048
#define NHEAD 16
#define HDIM 128
#define LDQ 6144   // fused QKV row stride

typedef __bf16 bf16_t;
typedef __bf16 bf16x2 __attribute__((ext_vector_type(2)));
typedef __bf16 bf16x4_t __attribute__((ext_vector_type(4)));
typedef __bf16 bf16x8 __attribute__((ext_vector_type(8)));
typedef float f32x4 __attribute__((ext_vector_type(4)));
typedef float f32x16 __attribute__((ext_vector_type(16)));
typedef unsigned u32x4 __attribute__((ext_vector_type(4)));

#define MFMA16(a, b, c) __builtin_amdgcn_mfma_f32_16x16x32_bf16(a, b, c, 0, 0, 0)
#define MFMA32(a, b, c) __builtin_amdgcn_mfma_f32_32x32x16_bf16(a, b, c, 0, 0, 0)
#define GLOAD_LDS(g, l) \
  __builtin_amdgcn_global_load_lds((const __attribute__((address_space(1))) void*)(g), \
                                   (__attribute__((address_space(3))) void*)(l), 16, 0, 0)

static __device__ inline unsigned pk2(float lo, float hi) {
  bf16x2 t; t[0] = (bf16_t)lo; t[1] = (bf16_t)hi;
  return __builtin_bit_cast(unsigned, t);
}

// ---------------- cast kernels ----------------
__global__ void cast_hidden(const float* __restrict__ in, bf16_t* __restrict__ out) {
  int i = blockIdx.x * 256 + threadIdx.x;
  float4 v = ((const float4*)in)[i];
  bf16x4_t b;
  b[0] = (bf16_t)v.x; b[1] = (bf16_t)v.y; b[2] = (bf16_t)v.z; b[3] = (bf16_t)v.w;
  ((bf16x4_t*)out)[i] = b;
}

__global__ void cast_weights(const float* __restrict__ a, const float* __restrict__ b,
                             const float* __restrict__ c, const float* __restrict__ d,
                             bf16_t* __restrict__ out) {
  const float* srcs[4] = {a, b, c, d};
  const float* src = srcs[blockIdx.y];
  bf16_t* dst = out + (size_t)blockIdx.y * (HID * HID);
  int i = blockIdx.x * 256 + threadIdx.x;
  float4 v = ((const float4*)src)[i];
  bf16x4_t o;
  o[0] = (bf16_t)v.x; o[1] = (bf16_t)v.y; o[2] = (bf16_t)v.z; o[3] = (bf16_t)v.w;
  ((bf16x4_t*)dst)[i] = o;
}

// ---------------- 256x256 8-phase GEMM: C = A * B^T (bf16, row-major) --------------
// BM=BN=256, BK=64, 8 waves (2Mx4N), 512 thr, LDS 128KB (2 tile-bufs x {A,B} x {k0,k1}).
// Schedule: 4 phases/K-tile = (k-half x m-half); stage 1 half-tile/phase;
// vmcnt(6) at phases 4 & 8 only; raw s_barrier; setprio around MFMA cluster.
__global__ __launch_bounds__(512, 2) void gemm256(
    const bf16_t* __restrict__ A, const bf16_t* __restrict__ Bw,
    bf16_t* __restrict__ Cb, float* __restrict__ Cf, int M, int N, int K) {
  __shared__ char smem[131072];
  const int tid = threadIdx.x, lane = tid & 63, wid = tid >> 6;
  const int wr = wid >> 2, wc = wid & 3;          // 2 x 4 wave grid
  const int lr = lane & 15, lg = lane >> 4;
  const int nwg = gridDim.x;
  const int lid = (blockIdx.x & 7) * (nwg >> 3) + (blockIdx.x >> 3);
  const int nbc = N >> 8;
  const int brow = lid / nbc, bcol = lid % nbc;
  const int NT = K >> 6;                           // K-tiles of 64

  const bf16_t* Ab = A + (size_t)(brow * 256) * K;
  const bf16_t* Bb = Bw + (size_t)(bcol * 256) * K;

  f32x4 acc[8][4] = {};
  bf16x8 af[4], bfr[4];
  const int swz = (lg ^ (lr & 3)) << 4;

  // Stage one 16KB half-tile (op: 0=A 1=B, k-half kh) of K-tile t_ (clamped).
  // LDS dest linear (wave-uniform base + lane*16); global source pre-swizzled
  // so swizzled ds_reads see the right data (rule 21 / T2).
#define STAGE_HALF(t_, op, kh)                                                        \
  {                                                                                   \
    int tt = (t_) < NT ? (t_) : NT - 1;                                               \
    const bf16_t* gsrc = (op) ? Bb : Ab;                                              \
    char* ldst = smem + (tt & 1) * 65536 + (op) * 32768 + (kh) * 16384;               \
    _Pragma("unroll") for (int is = 0; is < 2; ++is) {                                \
      int p = tid + is * 512;                                                         \
      int row = p >> 2, ch = p & 3;                                                   \
      GLOAD_LDS(gsrc + (size_t)row * K + tt * 64 + (kh) * 32 + ((ch ^ (row & 3)) * 8),\
                ldst + p * 16);                                                       \
    }                                                                                 \
  }

#define PHASE(cb, kh, mh, LOADB, STAGECALL, VM)                                       \
  {                                                                                   \
    _Pragma("unroll") for (int mf = 0; mf < 4; ++mf) {                                \
      int row = wr * 128 + (mh) * 64 + mf * 16 + lr;                                  \
      af[mf] = *(const bf16x8*)(smem + (cb) * 65536 + (kh) * 16384 + row * 64 + swz); \
    }                                                                                 \
    if (LOADB) {                                                                      \
      _Pragma("unroll") for (int nf = 0; nf < 4; ++nf) {                              \
        int row = wc * 64 + nf * 16 + lr;                                             \
        bfr[nf] = *(const bf16x8*)(smem + (cb) * 65536 + 32768 + (kh) * 16384 +       \
                                   row * 64 + swz);                                   \
      }                                                                               \
    }                                                                                 \
    STAGECALL;                                                                        \
    __builtin_amdgcn_s_barrier();                                                     \
    asm volatile("s_waitcnt lgkmcnt(0)" ::: "memory");                                \
    __builtin_amdgcn_sched_barrier(0);                                                \
    __builtin_amdgcn_s_setprio(1);                                                    \
    _Pragma("unroll") for (int mf = 0; mf < 4; ++mf)                                  \
      _Pragma("unroll") for (int nf = 0; nf < 4; ++nf)                                \
        acc[(mh) * 4 + mf][nf] = MFMA16(af[mf], bfr[nf], acc[(mh) * 4 + mf][nf]);     \
    __builtin_amdgcn_s_setprio(0);                                                    \
    if (VM) { asm volatile("s_waitcnt vmcnt(6)" ::: "memory"); }                      \
    __builtin_amdgcn_s_barrier();                                                     \
    __builtin_amdgcn_sched_barrier(0);                                                \
  }

  // Prologue: virtual iter -1 stages t0.{Bk0,Ak0,Bk1,Ak1} + t1.{Bk0,Ak0,Bk1}
  STAGE_HALF(0, 1, 0); STAGE_HALF(0, 0, 0); STAGE_HALF(0, 1, 1); STAGE_HALF(0, 0, 1);
  STAGE_HALF(1, 1, 0); STAGE_HALF(1, 0, 0); STAGE_HALF(1, 1, 1);
  asm volatile("s_waitcnt vmcnt(6)" ::: "memory");   // t0 complete; t1 in flight
  __builtin_amdgcn_s_barrier();
  __builtin_amdgcn_sched_barrier(0);

  const int NI = NT >> 1;     // 2 K-tiles per iteration (tile 2i -> buf0, 2i+1 -> buf1)
  for (int i = 0; i < NI; ++i) {
    const int t2 = 2 * i;
    PHASE(0, 0, 0, 1, STAGE_HALF(t2 + 1, 0, 1), 0);   // p1
    PHASE(0, 0, 1, 0, STAGE_HALF(t2 + 2, 1, 0), 0);   // p2
    PHASE(0, 1, 0, 1, STAGE_HALF(t2 + 2, 0, 0), 0);   // p3
    PHASE(0, 1, 1, 0, STAGE_HALF(t2 + 2, 1, 1), 1);   // p4 (vmcnt 6)
    PHASE(1, 0, 0, 1, STAGE_HALF(t2 + 2, 0, 1), 0);   // p5
    PHASE(1, 0, 1, 0, STAGE_HALF(t2 + 3, 1, 0), 0);   // p6
    PHASE(1, 1, 0, 1, STAGE_HALF(t2 + 3, 0, 0), 0);   // p7
    PHASE(1, 1, 1, 0, STAGE_HALF(t2 + 3, 1, 1), 1);   // p8 (vmcnt 6)
  }
#undef PHASE
#undef STAGE_HALF

#pragma unroll
  for (int mi = 0; mi < 8; ++mi)
#pragma unroll
    for (int nf = 0; nf < 4; ++nf)
#pragma unroll
      for (int r = 0; r < 4; ++r) {
        int row = brow * 256 + wr * 128 + (mi >> 2) * 64 + (mi & 3) * 16 + lg * 4 + r;
        int col = bcol * 256 + wc * 64 + nf * 16 + lr;
        float v = acc[mi][nf][r];
        if (Cf) Cf[(size_t)row * N + col] = v;
        else    Cb[(size_t)row * N + col] = (bf16_t)v;
      }
}

// ---------------- GEMM: C = A * B^T, 2-phase double-buffered (128x128) -------------
__global__ __launch_bounds__(256, 3) void gemm_bt(
    const bf16_t* __restrict__ A, const bf16_t* __restrict__ Bw,
    bf16_t* __restrict__ Cb, float* __restrict__ Cf,
    int M, int N, int K) {
  __shared__ bf16_t As[2][128 * 32];
  __shared__ bf16_t Bs[2][128 * 32];
  const int tid = threadIdx.x;
  const int lane = tid & 63, wid = tid >> 6;
  const int wr = wid >> 1, wc = wid & 1;
  const int lr = lane & 15, lg = lane >> 4;
  const int nwg = gridDim.x;
  const int lid = (blockIdx.x & 7) * (nwg >> 3) + (blockIdx.x >> 3);
  const int nbc = N >> 7;
  const int brow = lid / nbc, bcol = lid % nbc;

  f32x4 acc[4][4] = {};

  const int srow = tid >> 2, sch = tid & 3;
#define GSTAGE(k0, bb)                                                                   \
  {                                                                                      \
    _Pragma("unroll") for (int is = 0; is < 2; ++is) {                                   \
      int row = srow + is * 64;                                                          \
      GLOAD_LDS(A + (size_t)(brow * 128 + row) * K + (k0) + sch * 8,                     \
                &As[bb][(row * 4 + sch) * 8]);                                           \
      GLOAD_LDS(Bw + (size_t)(bcol * 128 + row) * K + (k0) + sch * 8,                    \
                &Bs[bb][(row * 4 + sch) * 8]);                                           \
    }                                                                                    \
  }

  GSTAGE(0, 0);
  __syncthreads();

  const int nt = K / 32;
  for (int t = 0; t < nt; ++t) {
    const int cb = t & 1;
    if (t + 1 < nt) GSTAGE((t + 1) * 32, cb ^ 1);
    bf16x8 af[4], bfr[4];
#pragma unroll
    for (int m = 0; m < 4; ++m)
      af[m] = *(const bf16x8*)(&As[cb][(wr * 64 + m * 16 + lr) * 32 + lg * 8]);
#pragma unroll
    for (int n = 0; n < 4; ++n)
      bfr[n] = *(const bf16x8*)(&Bs[cb][(wc * 64 + n * 16 + lr) * 32 + lg * 8]);
#pragma unroll
    for (int m = 0; m < 4; ++m)
#pragma unroll
      for (int n = 0; n < 4; ++n)
        acc[m][n] = MFMA16(af[m], bfr[n], acc[m][n]);
    __syncthreads();
  }
#undef GSTAGE

#pragma unroll
  for (int m = 0; m < 4; ++m)
#pragma unroll
    for (int n = 0; n < 4; ++n)
#pragma unroll
      for (int r = 0; r < 4; ++r) {
        int row = brow * 128 + wr * 64 + m * 16 + lg * 4 + r;
        int col = bcol * 128 + wc * 64 + n * 16 + lr;
        float v = acc[m][n][r];
        if (Cf) Cf[(size_t)row * N + col] = v;
        else    Cb[(size_t)row * N + col] = (bf16_t)v;
      }
}

// ---------------- RoPE in-place on fused QKV (Q gets pre-scaled by 1/sqrt(HD)) ----------
__global__ void rope_qk(bf16_t* __restrict__ QKV,
                        const float* __restrict__ cost, const float* __restrict__ sint) {
  const float SCALE = 0.08838834764831845f;  // 1/sqrt(128)
  int idx = blockIdx.x * 256 + threadIdx.x;            // total = 4096*16*8 = 524288
  int d8 = idx & 7;
  int t = idx >> 3;
  int h = t & 15;
  int row = t >> 4;
  int s = row & (SEQ - 1);
  size_t base = (size_t)row * LDQ + h * HDIM;
  const float4* cp = (const float4*)(cost + s * HDIM);
  const float4* sp = (const float4*)(sint + s * HDIM);
  float4 c0a = cp[d8 * 2], c0b = cp[d8 * 2 + 1];
  float4 c1a = cp[16 + d8 * 2], c1b = cp[16 + d8 * 2 + 1];
  float4 s0a = sp[d8 * 2], s0b = sp[d8 * 2 + 1];
  float4 s1a = sp[16 + d8 * 2], s1b = sp[16 + d8 * 2 + 1];
  float c0[8] = {c0a.x, c0a.y, c0a.z, c0a.w, c0b.x, c0b.y, c0b.z, c0b.w};
  float c1[8] = {c1a.x, c1a.y, c1a.z, c1a.w, c1b.x, c1b.y, c1b.z, c1b.w};
  float s0[8] = {s0a.x, s0a.y, s0a.z, s0a.w, s0b.x, s0b.y, s0b.z, s0b.w};
  float s1[8] = {s1a.x, s1a.y, s1a.z, s1a.w, s1b.x, s1b.y, s1b.z, s1b.w};

  bf16_t* Q = QKV;
  bf16_t* K = QKV + 2048;
  bf16x8 qlo = *(bf16x8*)(Q + base + d8 * 8);
  bf16x8 qhi = *(bf16x8*)(Q + base + 64 + d8 * 8);
  bf16x8 klo = *(bf16x8*)(K + base + d8 * 8);
  bf16x8 khi = *(bf16x8*)(K + base + 64 + d8 * 8);
  bf16x8 qlo2, qhi2, klo2, khi2;
#pragma unroll
  for (int j = 0; j < 8; ++j) {
    float q0 = (float)qlo[j], q1 = (float)qhi[j];
    qlo2[j] = (bf16_t)((q0 * c0[j] - q1 * s0[j]) * SCALE);
    qhi2[j] = (bf16_t)((q1 * c1[j] + q0 * s1[j]) * SCALE);
    float k0 = (float)klo[j], k1 = (float)khi[j];
    klo2[j] = (bf16_t)(k0 * c0[j] - k1 * s0[j]);
    khi2[j] = (bf16_t)(k1 * c1[j] + k0 * s1[j]);
  }
  *(bf16x8*)(Q + base + d8 * 8) = qlo2;
  *(bf16x8*)(Q + base + 64 + d8 * 8) = qhi2;
  *(bf16x8*)(K + base + d8 * 8) = klo2;
  *(bf16x8*)(K + base + 64 + d8 * 8) = khi2;
}

// ---------------- V transpose: Vf (B*S x H, ld=LDQ) -> Vt[b][h][d][s] ----------------
__global__ void transpose_v(const bf16_t* __restrict__ Vf, bf16_t* __restrict__ Vt) {
  __shared__ bf16_t t[32][33];
  int tx = threadIdx.x & 31, ty = threadIdx.x >> 5;
  int r0 = blockIdx.y * 32, c0 = blockIdx.x * 32;
#pragma unroll
  for (int j = 0; j < 4; ++j)
    t[ty + j * 8][tx] = Vf[(size_t)(r0 + ty + j * 8) * LDQ + c0 + tx];
  __syncthreads();
#pragma unroll
  for (int j = 0; j < 4; ++j) {
    int c = c0 + ty + j * 8;
    int r = r0 + tx;
    int h = c >> 7, d = c & 127, b = r >> 11, s = r & (SEQ - 1);
    Vt[(((size_t)(b * NHEAD + h)) * HDIM + d) * SEQ + s] = t[tx][ty + j * 8];
  }
}

// ---------------- flash attention fwd: swapped-QK 32x32, in-register softmax ----------
__global__ __launch_bounds__(512, 2) void flash_fwd(
    const bf16_t* __restrict__ Qf, const bf16_t* __restrict__ Kf,
    const bf16_t* __restrict__ Vt, const float* __restrict__ mask,
    bf16_t* __restrict__ AO) {
  __shared__ char smem[131072];          // K 2x32K | V 2x32K
  char* KsB = smem;
  char* VsB = smem + 65536;
  const int tid = threadIdx.x, lane = tid & 63, wid = tid >> 6;
  const int q32 = lane & 31, hi = lane >> 5;

  const int x = blockIdx.x;
  const int bh = x & 31, qt = x >> 5;
  const int b = bh >> 4, h = bh & 15;
  const int qg = qt * 256 + wid * 32 + q32;

  // Q fragments (B-operand): lane holds Q[q=lane&31][d = ds*16 + hi*8 + j]
  bf16x8 qf[8];
  const bf16_t* qptr = Qf + (size_t)(b * SEQ + qg) * LDQ + h * HDIM + hi * 8;
#pragma unroll
  for (int ds = 0; ds < 8; ++ds) qf[ds] = *(const bf16x8*)(qptr + ds * 16);

  const float* mp = mask + (size_t)b * SEQ * SEQ + (size_t)qg * SEQ + hi * 4;

  float mrun = -INFINITY, lpart = 0.f;
  f32x16 o[4] = {};

#define STAGE_KV(kt_, bb)                                                                \
  {                                                                                      \
    const int kb0_ = (kt_) * 128;                                                        \
    _Pragma("unroll") for (int is = 0; is < 4; ++is) {                                   \
      int p = tid + is * 512;                                                            \
      int row = p >> 4, ch = p & 15;                                                     \
      int src = (ch * 16) ^ ((row & 7) << 4);                                            \
      GLOAD_LDS((const char*)(Kf + (size_t)(b * SEQ + kb0_ + row) * LDQ + h * HDIM) +    \
                    src,                                                                 \
                KsB + (bb) * 32768 + p * 16);                                            \
      GLOAD_LDS((const char*)(Vt + (size_t)(bh * HDIM + row) * SEQ + kb0_) + src,        \
                VsB + (bb) * 32768 + p * 16);                                            \
    }                                                                                    \
  }

  STAGE_KV(0, 0);
  __syncthreads();

  const int NT = SEQ / 128;
  for (int kt = 0; kt < NT; ++kt) {
    const int cur = kt & 1;
    const int kb0 = kt * 128;
    if (kt + 1 < NT) STAGE_KV(kt + 1, cur ^ 1);

#pragma unroll
    for (int kb = 0; kb < 4; ++kb) {
      // init accumulator with mask (C[key][q]: key = (reg&3)+8*(reg>>2)+4*hi)
      f32x16 sacc;
#pragma unroll
      for (int g = 0; g < 4; ++g) {
        float4 m4 = *(const float4*)(mp + kb0 + kb * 32 + 8 * g);
        sacc[4 * g + 0] = m4.x; sacc[4 * g + 1] = m4.y;
        sacc[4 * g + 2] = m4.z; sacc[4 * g + 3] = m4.w;
      }
      // QK^T over d=128: A = K frag from LDS (row=key, k=d)
#pragma unroll
      for (int ds = 0; ds < 8; ++ds) {
        int row = kb * 32 + q32;
        bf16x8 kfr = *(const bf16x8*)(KsB + cur * 32768 + row * 256 +
                                      ((ds * 32 + hi * 16) ^ ((row & 7) << 4)));
        sacc = MFMA32(kfr, qf[ds], sacc);
      }

      // row max over this 32-key group (lane pair shares q)
      float mx = sacc[0];
#pragma unroll
      for (int r = 1; r < 16; ++r) mx = fmaxf(mx, sacc[r]);
      mx = fmaxf(mx, __shfl_xor(mx, 32, 64));
      // defer-max (T13)
      if (!__all(mx <= mrun + 8.f)) {
        float mnew = fmaxf(mrun, mx);
        float corr = __expf(mrun - mnew);
        mrun = mnew;
        lpart *= corr;
#pragma unroll
        for (int d0 = 0; d0 < 4; ++d0)
#pragma unroll
          for (int r = 0; r < 16; ++r) o[d0][r] *= corr;
      }

      // P = exp(s - m); per-lane partial row sum
      float p[16];
      float rs = 0.f;
#pragma unroll
      for (int r = 0; r < 16; ++r) {
        p[r] = __expf(sacc[r] - mrun);
        rs += p[r];
      }
      lpart += rs;

      // re-layout P to PV B-fragments and run PV for this 32-key group
#pragma unroll
      for (int s = 0; s < 2; ++s) {
        unsigned A1 = pk2(p[8 * s + 0], p[8 * s + 1]);
        unsigned A2 = pk2(p[8 * s + 2], p[8 * s + 3]);
        unsigned B1 = pk2(p[8 * s + 4], p[8 * s + 5]);
        unsigned B2 = pk2(p[8 * s + 6], p[8 * s + 7]);
        unsigned A1s = __shfl_xor(A1, 32, 64);
        unsigned A2s = __shfl_xor(A2, 32, 64);
        unsigned B1s = __shfl_xor(B1, 32, 64);
        unsigned B2s = __shfl_xor(B2, 32, 64);
        unsigned w0 = hi ? B1s : A1;
        unsigned w1 = hi ? B2s : A2;
        unsigned w2 = hi ? B1 : A1s;
        unsigned w3 = hi ? B2 : A2s;
        u32x4 W = {w0, w1, w2, w3};
        bf16x8 pav = __builtin_bit_cast(bf16x8, W);
        const int gs = kb * 2 + s;
#pragma unroll
        for (int d0 = 0; d0 < 4; ++d0) {
          int vrow = d0 * 32 + q32;
          bf16x8 vf = *(const bf16x8*)(VsB + cur * 32768 + vrow * 256 +
                                       ((gs * 32 + hi * 16) ^ ((vrow & 7) << 4)));
          o[d0] = MFMA32(vf, pav, o[d0]);
        }
      }
    }
    __syncthreads();
  }
#undef STAGE_KV

  // epilogue: full row sum, normalize, write AO (pack bf16 pairs)
  float l = lpart + __shfl_xor(lpart, 32, 64);
  float rl = 1.f / l;
  bf16_t* aorow = AO + (size_t)(b * SEQ + qg) * HID + h * HDIM;
#pragma unroll
  for (int d0 = 0; d0 < 4; ++d0)
#pragma unroll
    for (int g = 0; g < 4; ++g) {
      unsigned lo = pk2(o[d0][4 * g + 0] * rl, o[d0][4 * g + 1] * rl);
      unsigned hi2 = pk2(o[d0][4 * g + 2] * rl, o[d0][4 * g + 3] * rl);
      int d = d0 * 32 + 8 * g + 4 * hi;
      *(unsigned*)(aorow + d) = lo;
      *(unsigned*)(aorow + d + 2) = hi2;
    }
}

// ---------------- launch ----------------
extern "C" void kernel_launch(void* const* d_in, const int* in_sizes, int n_in,
                              void* d_out, int out_size, void* d_ws, size_t ws_size,
                              hipStream_t stream) {
  const float* hidden = (const float*)d_in[0];
  const float* cost   = (const float*)d_in[1];
  const float* sint   = (const float*)d_in[2];
  const float* mask   = (const float*)d_in[3];
  const float* Wq     = (const float*)d_in[4];
  const float* Wk     = (const float*)d_in[5];
  const float* Wv     = (const float*)d_in[6];
  const float* Wo     = (const float*)d_in[7];
  float* out = (float*)d_out;
  char* ws = (char*)d_ws;

  bf16_t* Af  = (bf16_t*)(ws + 0);
  bf16_t* Wqb = (bf16_t*)(ws + 16777216);
  bf16_t* Wob = (bf16_t*)(ws + 41943040);
  bf16_t* QKV = (bf16_t*)(ws + 50331648);
  bf16_t* Vt  = (bf16_t*)(ws + 0);
  bf16_t* AO  = (bf16_t*)(ws + 16777216);

  cast_hidden<<<8192, 256, 0, stream>>>(hidden, Af);
  cast_weights<<<dim3(4096, 4), 256, 0, stream>>>(Wq, Wk, Wv, Wo, Wqb);

  // fused QKV projection: A(4096x2048) * [Wq;Wk;Wv]^T (6144x2048) -> QKV (8-phase 256^2)
  gemm256<<<384, 512, 0, stream>>>(Af, Wqb, QKV, nullptr, 4096, LDQ, HID);

  rope_qk<<<2048, 256, 0, stream>>>(QKV, cost, sint);
  transpose_v<<<dim3(64, 128), 256, 0, stream>>>(QKV + 4096, Vt);

  flash_fwd<<<256, 512, 0, stream>>>(QKV, QKV + 2048, Vt, mask, AO);

  gemm_bt<<<512, 256, 0, stream>>>(AO, Wob, nullptr, out, 4096, HID, HID);
}

// Round 5
// 312.899 us; speedup vs baseline: 1.4331x; 1.0382x over previous
//
#include <hip/hip_runtime.h>
#include <hip/hip_bf16.h>
#include <math.h>

// B=2, S=2048, H=2048, NH=16, HD=128
#define SEQ 2048
#define HID 2048
#define NHEAD 16
#define HDIM 128
#define LDQ 6144   // fused QKV row stride

typedef __bf16 bf16_t;
typedef __bf16 bf16x2 __attribute__((ext_vector_type(2)));
typedef __bf16 bf16x4_t __attribute__((ext_vector_type(4)));
typedef __bf16 bf16x8 __attribute__((ext_vector_type(8)));
typedef float f32x4 __attribute__((ext_vector_type(4)));
typedef float f32x16 __attribute__((ext_vector_type(16)));
typedef unsigned u32x4 __attribute__((ext_vector_type(4)));

#define MFMA16(a, b, c) __builtin_amdgcn_mfma_f32_16x16x32_bf16(a, b, c, 0, 0, 0)
#define MFMA32(a, b, c) __builtin_amdgcn_mfma_f32_32x32x16_bf16(a, b, c, 0, 0, 0)
#define GLOAD_LDS(g, l) \
  __builtin_amdgcn_global_load_lds((const __attribute__((address_space(1))) void*)(g), \
                                   (__attribute__((address_space(3))) void*)(l), 16, 0, 0)

static __device__ inline unsigned pk2(float lo, float hi) {
  bf16x2 t; t[0] = (bf16_t)lo; t[1] = (bf16_t)hi;
  return __builtin_bit_cast(unsigned, t);
}

// ---------------- cast kernels ----------------
__global__ void cast_hidden(const float* __restrict__ in, bf16_t* __restrict__ out) {
  int i = blockIdx.x * 256 + threadIdx.x;
  float4 v = ((const float4*)in)[i];
  bf16x4_t b;
  b[0] = (bf16_t)v.x; b[1] = (bf16_t)v.y; b[2] = (bf16_t)v.z; b[3] = (bf16_t)v.w;
  ((bf16x4_t*)out)[i] = b;
}

__global__ void cast_weights(const float* __restrict__ a, const float* __restrict__ b,
                             const float* __restrict__ c, const float* __restrict__ d,
                             bf16_t* __restrict__ out) {
  const float* srcs[4] = {a, b, c, d};
  const float* src = srcs[blockIdx.y];
  bf16_t* dst = out + (size_t)blockIdx.y * (HID * HID);
  int i = blockIdx.x * 256 + threadIdx.x;
  float4 v = ((const float4*)src)[i];
  bf16x4_t o;
  o[0] = (bf16_t)v.x; o[1] = (bf16_t)v.y; o[2] = (bf16_t)v.z; o[3] = (bf16_t)v.w;
  ((bf16x4_t*)dst)[i] = o;
}

// ---------------- 256x256 8-phase GEMM: C = A * B^T (bf16, row-major) --------------
// BM=BN=256, BK=64, 8 waves (2Mx4N), 512 thr, LDS 128KB.
// Conflict-free swizzle: 16B-chunk = lg ^ ((row>>1)&3)  (slot = 4*(row&1)+chunk covers
// all 8 slots across each 8-lane group).  Grid fixed at 384 blocks (16x24 tiles);
// XCD x owns an 8x6 super-tile for L2 locality.
__global__ __launch_bounds__(512, 2) void gemm256(
    const bf16_t* __restrict__ A, const bf16_t* __restrict__ Bw,
    bf16_t* __restrict__ Cb, float* __restrict__ Cf, int M, int N, int K) {
  __shared__ char smem[131072];
  const int tid = threadIdx.x, lane = tid & 63, wid = tid >> 6;
  const int wr = wid >> 2, wc = wid & 3;          // 2 x 4 wave grid
  const int lr = lane & 15, lg = lane >> 4;
  // 8x6 super-tile per XCD (384 blocks = 16 x 24 tiles)
  const int xcd = blockIdx.x & 7, l = blockIdx.x >> 3;
  const int brow = (xcd >> 2) * 8 + l / 6;
  const int bcol = (xcd & 3) * 6 + l % 6;
  const int NT = K >> 6;                           // K-tiles of 64

  const bf16_t* Ab = A + (size_t)(brow * 256) * K;
  const bf16_t* Bb = Bw + (size_t)(bcol * 256) * K;

  f32x4 acc[8][4] = {};
  bf16x8 af[4], bfr[4];
  const int swz = (lg ^ ((lr >> 1) & 3)) << 4;     // conflict-free chunk select

  // Stage one 16KB half-tile (op: 0=A 1=B, k-half kh) of K-tile t_ (clamped).
  // LDS dest linear; global source pre-swizzled to match the read XOR (rule 21 / T2).
#define STAGE_HALF(t_, op, kh)                                                        \
  {                                                                                   \
    int tt = (t_) < NT ? (t_) : NT - 1;                                               \
    const bf16_t* gsrc = (op) ? Bb : Ab;                                              \
    char* ldst = smem + (tt & 1) * 65536 + (op) * 32768 + (kh) * 16384;               \
    _Pragma("unroll") for (int is = 0; is < 2; ++is) {                                \
      int p = tid + is * 512;                                                         \
      int row = p >> 2, ch = p & 3;                                                   \
      GLOAD_LDS(gsrc + (size_t)row * K + tt * 64 + (kh) * 32 +                        \
                    ((ch ^ ((row >> 1) & 3)) * 8),                                    \
                ldst + p * 16);                                                       \
    }                                                                                 \
  }

#define PHASE(cb, kh, mh, LOADB, STAGECALL, VM)                                       \
  {                                                                                   \
    _Pragma("unroll") for (int mf = 0; mf < 4; ++mf) {                                \
      int row = wr * 128 + (mh) * 64 + mf * 16 + lr;                                  \
      af[mf] = *(const bf16x8*)(smem + (cb) * 65536 + (kh) * 16384 + row * 64 + swz); \
    }                                                                                 \
    if (LOADB) {                                                                      \
      _Pragma("unroll") for (int nf = 0; nf < 4; ++nf) {                              \
        int row = wc * 64 + nf * 16 + lr;                                             \
        bfr[nf] = *(const bf16x8*)(smem + (cb) * 65536 + 32768 + (kh) * 16384 +       \
                                   row * 64 + swz);                                   \
      }                                                                               \
    }                                                                                 \
    STAGECALL;                                                                        \
    __builtin_amdgcn_s_barrier();                                                     \
    asm volatile("s_waitcnt lgkmcnt(0)" ::: "memory");                                \
    __builtin_amdgcn_sched_barrier(0);                                                \
    __builtin_amdgcn_s_setprio(1);                                                    \
    _Pragma("unroll") for (int mf = 0; mf < 4; ++mf)                                  \
      _Pragma("unroll") for (int nf = 0; nf < 4; ++nf)                                \
        acc[(mh) * 4 + mf][nf] = MFMA16(af[mf], bfr[nf], acc[(mh) * 4 + mf][nf]);     \
    __builtin_amdgcn_s_setprio(0);                                                    \
    if (VM) { asm volatile("s_waitcnt vmcnt(6)" ::: "memory"); }                      \
    __builtin_amdgcn_s_barrier();                                                     \
    __builtin_amdgcn_sched_barrier(0);                                                \
  }

  // Prologue: stage t0.{Bk0,Ak0,Bk1,Ak1} + t1.{Bk0,Ak0,Bk1}
  STAGE_HALF(0, 1, 0); STAGE_HALF(0, 0, 0); STAGE_HALF(0, 1, 1); STAGE_HALF(0, 0, 1);
  STAGE_HALF(1, 1, 0); STAGE_HALF(1, 0, 0); STAGE_HALF(1, 1, 1);
  asm volatile("s_waitcnt vmcnt(6)" ::: "memory");   // t0 complete; t1 in flight
  __builtin_amdgcn_s_barrier();
  __builtin_amdgcn_sched_barrier(0);

  const int NI = NT >> 1;     // 2 K-tiles per iteration
  for (int i = 0; i < NI; ++i) {
    const int t2 = 2 * i;
    PHASE(0, 0, 0, 1, STAGE_HALF(t2 + 1, 0, 1), 0);   // p1
    PHASE(0, 0, 1, 0, STAGE_HALF(t2 + 2, 1, 0), 0);   // p2
    PHASE(0, 1, 0, 1, STAGE_HALF(t2 + 2, 0, 0), 0);   // p3
    PHASE(0, 1, 1, 0, STAGE_HALF(t2 + 2, 1, 1), 1);   // p4 (vmcnt 6)
    PHASE(1, 0, 0, 1, STAGE_HALF(t2 + 2, 0, 1), 0);   // p5
    PHASE(1, 0, 1, 0, STAGE_HALF(t2 + 3, 1, 0), 0);   // p6
    PHASE(1, 1, 0, 1, STAGE_HALF(t2 + 3, 0, 0), 0);   // p7
    PHASE(1, 1, 1, 0, STAGE_HALF(t2 + 3, 1, 1), 1);   // p8 (vmcnt 6)
  }
#undef PHASE
#undef STAGE_HALF

#pragma unroll
  for (int mi = 0; mi < 8; ++mi)
#pragma unroll
    for (int nf = 0; nf < 4; ++nf)
#pragma unroll
      for (int r = 0; r < 4; ++r) {
        int row = brow * 256 + wr * 128 + (mi >> 2) * 64 + (mi & 3) * 16 + lg * 4 + r;
        int col = bcol * 256 + wc * 64 + nf * 16 + lr;
        float v = acc[mi][nf][r];
        if (Cf) Cf[(size_t)row * N + col] = v;
        else    Cb[(size_t)row * N + col] = (bf16_t)v;
      }
}

// ---------------- GEMM: C = A * B^T, 2-phase double-buffered (128x128) -------------
// Conflict-free swizzled LDS (chunk = lg ^ ((row>>1)&3), pre-swizzled source).
__global__ __launch_bounds__(256, 3) void gemm_bt(
    const bf16_t* __restrict__ A, const bf16_t* __restrict__ Bw,
    bf16_t* __restrict__ Cb, float* __restrict__ Cf,
    int M, int N, int K) {
  __shared__ bf16_t As[2][128 * 32];
  __shared__ bf16_t Bs[2][128 * 32];
  const int tid = threadIdx.x;
  const int lane = tid & 63, wid = tid >> 6;
  const int wr = wid >> 1, wc = wid & 1;
  const int lr = lane & 15, lg = lane >> 4;
  const int nwg = gridDim.x;
  const int lid = (blockIdx.x & 7) * (nwg >> 3) + (blockIdx.x >> 3);
  const int nbc = N >> 7;
  const int brow = lid / nbc, bcol = lid % nbc;

  f32x4 acc[4][4] = {};
  const int swz = lg ^ ((lr >> 1) & 3);

  const int srow = tid >> 2, sch = tid & 3;
#define GSTAGE(k0, bb)                                                                   \
  {                                                                                      \
    _Pragma("unroll") for (int is = 0; is < 2; ++is) {                                   \
      int row = srow + is * 64;                                                          \
      int g = (sch ^ ((row >> 1) & 3)) * 8;                                              \
      GLOAD_LDS(A + (size_t)(brow * 128 + row) * K + (k0) + g,                           \
                &As[bb][(row * 4 + sch) * 8]);                                           \
      GLOAD_LDS(Bw + (size_t)(bcol * 128 + row) * K + (k0) + g,                          \
                &Bs[bb][(row * 4 + sch) * 8]);                                           \
    }                                                                                    \
  }

  GSTAGE(0, 0);
  __syncthreads();

  const int nt = K / 32;
  for (int t = 0; t < nt; ++t) {
    const int cb = t & 1;
    if (t + 1 < nt) GSTAGE((t + 1) * 32, cb ^ 1);
    bf16x8 af[4], bfr[4];
#pragma unroll
    for (int m = 0; m < 4; ++m)
      af[m] = *(const bf16x8*)(&As[cb][(wr * 64 + m * 16 + lr) * 32 + swz * 8]);
#pragma unroll
    for (int n = 0; n < 4; ++n)
      bfr[n] = *(const bf16x8*)(&Bs[cb][(wc * 64 + n * 16 + lr) * 32 + swz * 8]);
#pragma unroll
    for (int m = 0; m < 4; ++m)
#pragma unroll
      for (int n = 0; n < 4; ++n)
        acc[m][n] = MFMA16(af[m], bfr[n], acc[m][n]);
    __syncthreads();
  }
#undef GSTAGE

#pragma unroll
  for (int m = 0; m < 4; ++m)
#pragma unroll
    for (int n = 0; n < 4; ++n)
#pragma unroll
      for (int r = 0; r < 4; ++r) {
        int row = brow * 128 + wr * 64 + m * 16 + lg * 4 + r;
        int col = bcol * 128 + wc * 64 + n * 16 + lr;
        float v = acc[m][n][r];
        if (Cf) Cf[(size_t)row * N + col] = v;
        else    Cb[(size_t)row * N + col] = (bf16_t)v;
      }
}

// ---------------- RoPE in-place on fused QKV (Q gets pre-scaled by 1/sqrt(HD)) ----------
__global__ void rope_qk(bf16_t* __restrict__ QKV,
                        const float* __restrict__ cost, const float* __restrict__ sint) {
  const float SCALE = 0.08838834764831845f;  // 1/sqrt(128)
  int idx = blockIdx.x * 256 + threadIdx.x;            // total = 4096*16*8 = 524288
  int d8 = idx & 7;
  int t = idx >> 3;
  int h = t & 15;
  int row = t >> 4;
  int s = row & (SEQ - 1);
  size_t base = (size_t)row * LDQ + h * HDIM;
  const float4* cp = (const float4*)(cost + s * HDIM);
  const float4* sp = (const float4*)(sint + s * HDIM);
  float4 c0a = cp[d8 * 2], c0b = cp[d8 * 2 + 1];
  float4 c1a = cp[16 + d8 * 2], c1b = cp[16 + d8 * 2 + 1];
  float4 s0a = sp[d8 * 2], s0b = sp[d8 * 2 + 1];
  float4 s1a = sp[16 + d8 * 2], s1b = sp[16 + d8 * 2 + 1];
  float c0[8] = {c0a.x, c0a.y, c0a.z, c0a.w, c0b.x, c0b.y, c0b.z, c0b.w};
  float c1[8] = {c1a.x, c1a.y, c1a.z, c1a.w, c1b.x, c1b.y, c1b.z, c1b.w};
  float s0[8] = {s0a.x, s0a.y, s0a.z, s0a.w, s0b.x, s0b.y, s0b.z, s0b.w};
  float s1[8] = {s1a.x, s1a.y, s1a.z, s1a.w, s1b.x, s1b.y, s1b.z, s1b.w};

  bf16_t* Q = QKV;
  bf16_t* K = QKV + 2048;
  bf16x8 qlo = *(bf16x8*)(Q + base + d8 * 8);
  bf16x8 qhi = *(bf16x8*)(Q + base + 64 + d8 * 8);
  bf16x8 klo = *(bf16x8*)(K + base + d8 * 8);
  bf16x8 khi = *(bf16x8*)(K + base + 64 + d8 * 8);
  bf16x8 qlo2, qhi2, klo2, khi2;
#pragma unroll
  for (int j = 0; j < 8; ++j) {
    float q0 = (float)qlo[j], q1 = (float)qhi[j];
    qlo2[j] = (bf16_t)((q0 * c0[j] - q1 * s0[j]) * SCALE);
    qhi2[j] = (bf16_t)((q1 * c1[j] + q0 * s1[j]) * SCALE);
    float k0 = (float)klo[j], k1 = (float)khi[j];
    klo2[j] = (bf16_t)(k0 * c0[j] - k1 * s0[j]);
    khi2[j] = (bf16_t)(k1 * c1[j] + k0 * s1[j]);
  }
  *(bf16x8*)(Q + base + d8 * 8) = qlo2;
  *(bf16x8*)(Q + base + 64 + d8 * 8) = qhi2;
  *(bf16x8*)(K + base + d8 * 8) = klo2;
  *(bf16x8*)(K + base + 64 + d8 * 8) = khi2;
}

// ---------------- V transpose: Vf (B*S x H, ld=LDQ) -> Vt[b][h][d][s] ----------------
__global__ void transpose_v(const bf16_t* __restrict__ Vf, bf16_t* __restrict__ Vt) {
  __shared__ bf16_t t[32][33];
  int tx = threadIdx.x & 31, ty = threadIdx.x >> 5;
  int r0 = blockIdx.y * 32, c0 = blockIdx.x * 32;
#pragma unroll
  for (int j = 0; j < 4; ++j)
    t[ty + j * 8][tx] = Vf[(size_t)(r0 + ty + j * 8) * LDQ + c0 + tx];
  __syncthreads();
#pragma unroll
  for (int j = 0; j < 4; ++j) {
    int c = c0 + ty + j * 8;
    int r = r0 + tx;
    int h = c >> 7, d = c & 127, b = r >> 11, s = r & (SEQ - 1);
    Vt[(((size_t)(b * NHEAD + h)) * HDIM + d) * SEQ + s] = t[tx][ty + j * 8];
  }
}

// ---------------- flash attention fwd: swapped-QK 32x32, in-register softmax ----------
__global__ __launch_bounds__(512, 2) void flash_fwd(
    const bf16_t* __restrict__ Qf, const bf16_t* __restrict__ Kf,
    const bf16_t* __restrict__ Vt, const float* __restrict__ mask,
    bf16_t* __restrict__ AO) {
  __shared__ char smem[131072];          // K 2x32K | V 2x32K
  char* KsB = smem;
  char* VsB = smem + 65536;
  const int tid = threadIdx.x, lane = tid & 63, wid = tid >> 6;
  const int q32 = lane & 31, hi = lane >> 5;

  const int x = blockIdx.x;
  const int bh = x & 31, qt = x >> 5;
  const int b = bh >> 4, h = bh & 15;
  const int qg = qt * 256 + wid * 32 + q32;

  // Q fragments (B-operand): lane holds Q[q=lane&31][d = ds*16 + hi*8 + j]
  bf16x8 qf[8];
  const bf16_t* qptr = Qf + (size_t)(b * SEQ + qg) * LDQ + h * HDIM + hi * 8;
#pragma unroll
  for (int ds = 0; ds < 8; ++ds) qf[ds] = *(const bf16x8*)(qptr + ds * 16);

  const float* mp = mask + (size_t)b * SEQ * SEQ + (size_t)qg * SEQ + hi * 4;

  float mrun = -INFINITY, lpart = 0.f;
  f32x16 o[4] = {};

#define STAGE_KV(kt_, bb)                                                                \
  {                                                                                      \
    const int kb0_ = (kt_) * 128;                                                        \
    _Pragma("unroll") for (int is = 0; is < 4; ++is) {                                   \
      int p = tid + is * 512;                                                            \
      int row = p >> 4, ch = p & 15;                                                     \
      int src = (ch * 16) ^ ((row & 7) << 4);                                            \
      GLOAD_LDS((const char*)(Kf + (size_t)(b * SEQ + kb0_ + row) * LDQ + h * HDIM) +    \
                    src,                                                                 \
                KsB + (bb) * 32768 + p * 16);                                            \
      GLOAD_LDS((const char*)(Vt + (size_t)(bh * HDIM + row) * SEQ + kb0_) + src,        \
                VsB + (bb) * 32768 + p * 16);                                            \
    }                                                                                    \
  }

  STAGE_KV(0, 0);
  __syncthreads();

  const int NT = SEQ / 128;
  for (int kt = 0; kt < NT; ++kt) {
    const int cur = kt & 1;
    const int kb0 = kt * 128;
    if (kt + 1 < NT) STAGE_KV(kt + 1, cur ^ 1);

#pragma unroll
    for (int kb = 0; kb < 4; ++kb) {
      // init accumulator with mask (C[key][q]: key = (reg&3)+8*(reg>>2)+4*hi)
      f32x16 sacc;
#pragma unroll
      for (int g = 0; g < 4; ++g) {
        float4 m4 = *(const float4*)(mp + kb0 + kb * 32 + 8 * g);
        sacc[4 * g + 0] = m4.x; sacc[4 * g + 1] = m4.y;
        sacc[4 * g + 2] = m4.z; sacc[4 * g + 3] = m4.w;
      }
      // QK^T over d=128: A = K frag from LDS (row=key, k=d)
#pragma unroll
      for (int ds = 0; ds < 8; ++ds) {
        int row = kb * 32 + q32;
        bf16x8 kfr = *(const bf16x8*)(KsB + cur * 32768 + row * 256 +
                                      ((ds * 32 + hi * 16) ^ ((row & 7) << 4)));
        sacc = MFMA32(kfr, qf[ds], sacc);
      }

      // row max over this 32-key group (lane pair shares q)
      float mx = sacc[0];
#pragma unroll
      for (int r = 1; r < 16; ++r) mx = fmaxf(mx, sacc[r]);
      mx = fmaxf(mx, __shfl_xor(mx, 32, 64));
      // defer-max (T13)
      if (!__all(mx <= mrun + 8.f)) {
        float mnew = fmaxf(mrun, mx);
        float corr = __expf(mrun - mnew);
        mrun = mnew;
        lpart *= corr;
#pragma unroll
        for (int d0 = 0; d0 < 4; ++d0)
#pragma unroll
          for (int r = 0; r < 16; ++r) o[d0][r] *= corr;
      }

      // P = exp(s - m); per-lane partial row sum
      float p[16];
      float rs = 0.f;
#pragma unroll
      for (int r = 0; r < 16; ++r) {
        p[r] = __expf(sacc[r] - mrun);
        rs += p[r];
      }
      lpart += rs;

      // re-layout P to PV B-fragments and run PV for this 32-key group
#pragma unroll
      for (int s = 0; s < 2; ++s) {
        unsigned A1 = pk2(p[8 * s + 0], p[8 * s + 1]);
        unsigned A2 = pk2(p[8 * s + 2], p[8 * s + 3]);
        unsigned B1 = pk2(p[8 * s + 4], p[8 * s + 5]);
        unsigned B2 = pk2(p[8 * s + 6], p[8 * s + 7]);
        unsigned A1s = __shfl_xor(A1, 32, 64);
        unsigned A2s = __shfl_xor(A2, 32, 64);
        unsigned B1s = __shfl_xor(B1, 32, 64);
        unsigned B2s = __shfl_xor(B2, 32, 64);
        unsigned w0 = hi ? B1s : A1;
        unsigned w1 = hi ? B2s : A2;
        unsigned w2 = hi ? B1 : A1s;
        unsigned w3 = hi ? B2 : A2s;
        u32x4 W = {w0, w1, w2, w3};
        bf16x8 pav = __builtin_bit_cast(bf16x8, W);
        const int gs = kb * 2 + s;
#pragma unroll
        for (int d0 = 0; d0 < 4; ++d0) {
          int vrow = d0 * 32 + q32;
          bf16x8 vf = *(const bf16x8*)(VsB + cur * 32768 + vrow * 256 +
                                       ((gs * 32 + hi * 16) ^ ((vrow & 7) << 4)));
          o[d0] = MFMA32(vf, pav, o[d0]);
        }
      }
    }
    __syncthreads();
  }
#undef STAGE_KV

  // epilogue: full row sum, normalize, write AO (pack bf16 pairs)
  float l = lpart + __shfl_xor(lpart, 32, 64);
  float rl = 1.f / l;
  bf16_t* aorow = AO + (size_t)(b * SEQ + qg) * HID + h * HDIM;
#pragma unroll
  for (int d0 = 0; d0 < 4; ++d0)
#pragma unroll
    for (int g = 0; g < 4; ++g) {
      unsigned lo = pk2(o[d0][4 * g + 0] * rl, o[d0][4 * g + 1] * rl);
      unsigned hi2 = pk2(o[d0][4 * g + 2] * rl, o[d0][4 * g + 3] * rl);
      int d = d0 * 32 + 8 * g + 4 * hi;
      *(unsigned*)(aorow + d) = lo;
      *(unsigned*)(aorow + d + 2) = hi2;
    }
}

// ---------------- launch ----------------
extern "C" void kernel_launch(void* const* d_in, const int* in_sizes, int n_in,
                              void* d_out, int out_size, void* d_ws, size_t ws_size,
                              hipStream_t stream) {
  const float* hidden = (const float*)d_in[0];
  const float* cost   = (const float*)d_in[1];
  const float* sint   = (const float*)d_in[2];
  const float* mask   = (const float*)d_in[3];
  const float* Wq     = (const float*)d_in[4];
  const float* Wk     = (const float*)d_in[5];
  const float* Wv     = (const float*)d_in[6];
  const float* Wo     = (const float*)d_in[7];
  float* out = (float*)d_out;
  char* ws = (char*)d_ws;

  bf16_t* Af  = (bf16_t*)(ws + 0);
  bf16_t* Wqb = (bf16_t*)(ws + 16777216);
  bf16_t* Wob = (bf16_t*)(ws + 41943040);
  bf16_t* QKV = (bf16_t*)(ws + 50331648);
  bf16_t* Vt  = (bf16_t*)(ws + 0);
  bf16_t* AO  = (bf16_t*)(ws + 16777216);

  cast_hidden<<<8192, 256, 0, stream>>>(hidden, Af);
  cast_weights<<<dim3(4096, 4), 256, 0, stream>>>(Wq, Wk, Wv, Wo, Wqb);

  // fused QKV projection: A(4096x2048) * [Wq;Wk;Wv]^T (6144x2048) -> QKV (8-phase 256^2)
  gemm256<<<384, 512, 0, stream>>>(Af, Wqb, QKV, nullptr, 4096, LDQ, HID);

  rope_qk<<<2048, 256, 0, stream>>>(QKV, cost, sint);
  transpose_v<<<dim3(64, 128), 256, 0, stream>>>(QKV + 4096, Vt);

  flash_fwd<<<256, 512, 0, stream>>>(QKV, QKV + 2048, Vt, mask, AO);

  gemm_bt<<<512, 256, 0, stream>>>(AO, Wob, nullptr, out, 4096, HID, HID);
}